// Round 1
// baseline (2956.130 us; speedup 1.0000x reference)
//
#include <hip/hip_runtime.h>
#include <math.h>

#define LNUM 16
#define D 256
#define FF 512
#define NH 8
#define NE 12
#define HD 32
#define BB 4
#define SS 512
#define NT 2048      // B*S
#define EPS 1e-5f
#define MAXT 80
#define PADROWS 4864

// ---------------- embedding gather ----------------
__global__ __launch_bounds__(256) void k_embed(const int* __restrict__ tok,
                                               const float* __restrict__ emb,
                                               float* __restrict__ x) {
  int n = blockIdx.x, t = threadIdx.x;
  x[(size_t)n * D + t] = emb[(size_t)tok[n] * D + t];
}

// ---------------- QKV projection: out = x@W + b (one of q/k/v per blockIdx.z) ----------------
__global__ __launch_bounds__(256) void k_qkv(
    const float* __restrict__ x,
    const float* __restrict__ Wq, const float* __restrict__ bq,
    const float* __restrict__ Wk, const float* __restrict__ bk,
    const float* __restrict__ Wv, const float* __restrict__ bv,
    float* __restrict__ qo, float* __restrict__ ko, float* __restrict__ vo) {
  const float* W; const float* bias; float* out;
  if (blockIdx.z == 0)      { W = Wq; bias = bq; out = qo; }
  else if (blockIdx.z == 1) { W = Wk; bias = bk; out = ko; }
  else                      { W = Wv; bias = bv; out = vo; }
  const int row0 = blockIdx.x * 64, col0 = blockIdx.y * 64;
  __shared__ float As[64][17];
  __shared__ float Bs[16][68];
  const int tid = threadIdx.x, ty = tid >> 4, tx = tid & 15;
  const int ar = tid >> 2, ak = (tid & 3) * 4;
  const int bkk = tid >> 4, bj = (tid & 15) * 4;
  float acc[4][4] = {};
  for (int k0 = 0; k0 < D; k0 += 16) {
    float4 a4 = *reinterpret_cast<const float4*>(x + (size_t)(row0 + ar) * D + k0 + ak);
    float4 b4 = *reinterpret_cast<const float4*>(W + (size_t)(k0 + bkk) * D + col0 + bj);
    As[ar][ak] = a4.x; As[ar][ak + 1] = a4.y; As[ar][ak + 2] = a4.z; As[ar][ak + 3] = a4.w;
    *reinterpret_cast<float4*>(&Bs[bkk][bj]) = b4;
    __syncthreads();
#pragma unroll
    for (int kk = 0; kk < 16; kk++) {
      float a[4];
#pragma unroll
      for (int i = 0; i < 4; i++) a[i] = As[ty * 4 + i][kk];
      float4 b = *reinterpret_cast<const float4*>(&Bs[kk][tx * 4]);
#pragma unroll
      for (int i = 0; i < 4; i++) {
        acc[i][0] += a[i] * b.x; acc[i][1] += a[i] * b.y;
        acc[i][2] += a[i] * b.z; acc[i][3] += a[i] * b.w;
      }
    }
    __syncthreads();
  }
#pragma unroll
  for (int i = 0; i < 4; i++) {
    float4 r;
    r.x = acc[i][0] + bias[col0 + tx * 4 + 0];
    r.y = acc[i][1] + bias[col0 + tx * 4 + 1];
    r.z = acc[i][2] + bias[col0 + tx * 4 + 2];
    r.w = acc[i][3] + bias[col0 + tx * 4 + 3];
    *reinterpret_cast<float4*>(out + (size_t)(row0 + ty * 4 + i) * D + col0 + tx * 4) = r;
  }
}

// ---------------- flash-style fp32 causal attention (no 1/sqrt(d) scale, per reference) ----------------
__global__ __launch_bounds__(256) void k_attn(const float* __restrict__ q,
                                              const float* __restrict__ k,
                                              const float* __restrict__ v,
                                              float* __restrict__ o) {
  const int rt = blockIdx.x, bh = blockIdx.y;
  const int b = bh >> 3, h = bh & 7;
  const int row0 = rt * 64;
  __shared__ float Qs[64][33], Ks[64][33], Vs[64][33], Ps[64][68];
  const int tid = threadIdx.x, ty = tid >> 4, tx = tid & 15;
  const int lr = tid >> 2, lw = (tid & 3) * 8;
  {
    const float* qp = q + (size_t)(b * SS + row0 + lr) * D + h * HD + lw;
    float4 q0 = *reinterpret_cast<const float4*>(qp);
    float4 q1 = *reinterpret_cast<const float4*>(qp + 4);
    Qs[lr][lw + 0] = q0.x; Qs[lr][lw + 1] = q0.y; Qs[lr][lw + 2] = q0.z; Qs[lr][lw + 3] = q0.w;
    Qs[lr][lw + 4] = q1.x; Qs[lr][lw + 5] = q1.y; Qs[lr][lw + 6] = q1.z; Qs[lr][lw + 7] = q1.w;
  }
  float oacc[4][2] = {};
  float mrow[4], lsum[4];
#pragma unroll
  for (int i = 0; i < 4; i++) { mrow[i] = -1e30f; lsum[i] = 0.f; }

  for (int ct = 0; ct <= rt; ct++) {
    __syncthreads();
    {
      const float* kp = k + (size_t)(b * SS + ct * 64 + lr) * D + h * HD + lw;
      const float* vp = v + (size_t)(b * SS + ct * 64 + lr) * D + h * HD + lw;
      float4 k0 = *reinterpret_cast<const float4*>(kp);
      float4 k1 = *reinterpret_cast<const float4*>(kp + 4);
      float4 v0 = *reinterpret_cast<const float4*>(vp);
      float4 v1 = *reinterpret_cast<const float4*>(vp + 4);
      Ks[lr][lw + 0] = k0.x; Ks[lr][lw + 1] = k0.y; Ks[lr][lw + 2] = k0.z; Ks[lr][lw + 3] = k0.w;
      Ks[lr][lw + 4] = k1.x; Ks[lr][lw + 5] = k1.y; Ks[lr][lw + 6] = k1.z; Ks[lr][lw + 7] = k1.w;
      Vs[lr][lw + 0] = v0.x; Vs[lr][lw + 1] = v0.y; Vs[lr][lw + 2] = v0.z; Vs[lr][lw + 3] = v0.w;
      Vs[lr][lw + 4] = v1.x; Vs[lr][lw + 5] = v1.y; Vs[lr][lw + 6] = v1.z; Vs[lr][lw + 7] = v1.w;
    }
    __syncthreads();
    float sc[4][4] = {};
#pragma unroll
    for (int w = 0; w < HD; w++) {
      float a[4], bb2[4];
#pragma unroll
      for (int i = 0; i < 4; i++) a[i] = Qs[ty * 4 + i][w];
#pragma unroll
      for (int j = 0; j < 4; j++) bb2[j] = Ks[tx * 4 + j][w];
#pragma unroll
      for (int i = 0; i < 4; i++)
#pragma unroll
        for (int j = 0; j < 4; j++) sc[i][j] += a[i] * bb2[j];
    }
    if (ct == rt) {
#pragma unroll
      for (int i = 0; i < 4; i++)
#pragma unroll
        for (int j = 0; j < 4; j++)
          if (tx * 4 + j > ty * 4 + i) sc[i][j] = -1e30f;
    }
#pragma unroll
    for (int i = 0; i < 4; i++) {
      float mt = fmaxf(fmaxf(sc[i][0], sc[i][1]), fmaxf(sc[i][2], sc[i][3]));
      for (int msk = 1; msk < 16; msk <<= 1) mt = fmaxf(mt, __shfl_xor(mt, msk, 16));
      float mn = fmaxf(mrow[i], mt);
      float scal = expf(mrow[i] - mn);
      float p0 = expf(sc[i][0] - mn), p1 = expf(sc[i][1] - mn);
      float p2 = expf(sc[i][2] - mn), p3 = expf(sc[i][3] - mn);
      float rs = p0 + p1 + p2 + p3;
      for (int msk = 1; msk < 16; msk <<= 1) rs += __shfl_xor(rs, msk, 16);
      lsum[i] = lsum[i] * scal + rs;
      mrow[i] = mn;
      oacc[i][0] *= scal; oacc[i][1] *= scal;
      Ps[ty * 4 + i][tx * 4 + 0] = p0;
      Ps[ty * 4 + i][tx * 4 + 1] = p1;
      Ps[ty * 4 + i][tx * 4 + 2] = p2;
      Ps[ty * 4 + i][tx * 4 + 3] = p3;
    }
    __syncthreads();
#pragma unroll 8
    for (int t2 = 0; t2 < 64; t2++) {
      float v0 = Vs[t2][tx * 2], v1 = Vs[t2][tx * 2 + 1];
#pragma unroll
      for (int i = 0; i < 4; i++) {
        float pp = Ps[ty * 4 + i][t2];
        oacc[i][0] += pp * v0; oacc[i][1] += pp * v1;
      }
    }
  }
#pragma unroll
  for (int i = 0; i < 4; i++) {
    float inv = 1.f / lsum[i];
    size_t base = (size_t)(b * SS + row0 + ty * 4 + i) * D + h * HD + tx * 2;
    o[base + 0] = oacc[i][0] * inv;
    o[base + 1] = oacc[i][1] * inv;
  }
}

// ---------------- residual + LN1 + gate logits + top-2 ----------------
__global__ __launch_bounds__(256) void k_ln1gate(
    const float* __restrict__ o, const float* __restrict__ x,
    const float* __restrict__ s1, const float* __restrict__ b1,
    const float* __restrict__ gW, const float* __restrict__ gb,
    float* __restrict__ norm, int* __restrict__ eidx) {
  const int n = blockIdx.x, t = threadIdx.x;
  __shared__ float red[256];
  __shared__ float gl[NE];
  float val = o[(size_t)n * D + t] + x[(size_t)n * D + t];
  red[t] = val; __syncthreads();
  for (int s = 128; s > 0; s >>= 1) { if (t < s) red[t] += red[t + s]; __syncthreads(); }
  float m = red[0] * (1.f / D); __syncthreads();
  float df = val - m;
  red[t] = df * df; __syncthreads();
  for (int s = 128; s > 0; s >>= 1) { if (t < s) red[t] += red[t + s]; __syncthreads(); }
  float rstd = rsqrtf(red[0] * (1.f / D) + EPS); __syncthreads();
  float nv = df * rstd * s1[t] + b1[t];
  norm[(size_t)n * D + t] = nv;
  red[t] = nv; __syncthreads();
  if (t < NE) {
    float acc = gb[t];
    for (int d2 = 0; d2 < D; d2++) acc += red[d2] * gW[d2 * NE + t];
    gl[t] = acc;
  }
  __syncthreads();
  if (t == 0) {
    int i1 = 0; float v1 = gl[0];
    for (int e = 1; e < NE; e++) if (gl[e] > v1) { v1 = gl[e]; i1 = e; }
    int i2 = -1; float v2 = -3.4e38f;
    for (int e = 0; e < NE; e++) if (e != i1 && gl[e] > v2) { v2 = gl[e]; i2 = e; }
    eidx[n * 2 + 0] = i1;
    eidx[n * 2 + 1] = i2;
  }
}

// ---------------- routing: counts -> padded tiles -> scatter ----------------
__global__ __launch_bounds__(256) void k_route(const int* __restrict__ eidx,
                                               int* __restrict__ rlist, int* __restrict__ tokpos,
                                               int* __restrict__ te, int* __restrict__ tbase,
                                               int* __restrict__ tnv) {
  __shared__ int cnt[NE], cur[NE], poff[NE];
  const int t = threadIdx.x;
  if (t < NE) { cnt[t] = 0; cur[t] = 0; }
  __syncthreads();
  for (int n = t; n < NT; n += 256) {
    atomicAdd(&cnt[eidx[n * 2 + 0]], 1);
    atomicAdd(&cnt[eidx[n * 2 + 1]], 1);
  }
  __syncthreads();
  if (t == 0) {
    int off = 0, ti = 0;
    for (int e = 0; e < NE; e++) {
      poff[e] = off;
      int nt = (cnt[e] + 63) >> 6;
      for (int tt = 0; tt < nt; tt++) {
        te[ti] = e; tbase[ti] = off + tt * 64;
        int rem = cnt[e] - tt * 64; tnv[ti] = rem < 64 ? rem : 64;
        ti++;
      }
      off += nt * 64;
    }
    for (; ti < MAXT; ti++) te[ti] = -1;
  }
  __syncthreads();
  for (int n = t; n < NT; n += 256) {
#pragma unroll
    for (int s2 = 0; s2 < 2; s2++) {
      int e = eidx[n * 2 + s2];
      int pos = atomicAdd(&cur[e], 1);
      int row = poff[e] + pos;
      rlist[row] = n;
      tokpos[n * 2 + s2] = row;
    }
  }
}

// ---------------- MoE up-projection: h = silu(norm@W1+b1) * (norm@Wg+bg), grouped per expert ----------------
__global__ __launch_bounds__(256) void k_ff1(
    const float* __restrict__ norm, const int* __restrict__ rlist,
    const int* __restrict__ te, const int* __restrict__ tbase, const int* __restrict__ tnv,
    const float* __restrict__ W1, const float* __restrict__ b1f,
    const float* __restrict__ Wg, const float* __restrict__ bgf,
    float* __restrict__ hbuf) {
  const int mt = blockIdx.x;
  const int e = te[mt];
  if (e < 0) return;
  const int base = tbase[mt], nv = tnv[mt];
  const int col0 = blockIdx.y * 64;
  const float* W1e = W1 + (size_t)e * D * FF;
  const float* Wge = Wg + (size_t)e * D * FF;
  __shared__ float As[64][17];
  __shared__ float Bs1[16][68], Bs2[16][68];
  __shared__ int rows[64];
  const int tid = threadIdx.x, ty = tid >> 4, tx = tid & 15;
  if (tid < 64) rows[tid] = (tid < nv) ? rlist[base + tid] : 0;
  __syncthreads();
  float c1[4][4] = {}, c2[4][4] = {};
  const int ar = tid >> 2, ak = (tid & 3) * 4;
  const int bkk = tid >> 4, bj = (tid & 15) * 4;
  for (int k0 = 0; k0 < D; k0 += 16) {
    float4 a4 = *reinterpret_cast<const float4*>(norm + (size_t)rows[ar] * D + k0 + ak);
    float4 b14 = *reinterpret_cast<const float4*>(W1e + (size_t)(k0 + bkk) * FF + col0 + bj);
    float4 b24 = *reinterpret_cast<const float4*>(Wge + (size_t)(k0 + bkk) * FF + col0 + bj);
    As[ar][ak] = a4.x; As[ar][ak + 1] = a4.y; As[ar][ak + 2] = a4.z; As[ar][ak + 3] = a4.w;
    *reinterpret_cast<float4*>(&Bs1[bkk][bj]) = b14;
    *reinterpret_cast<float4*>(&Bs2[bkk][bj]) = b24;
    __syncthreads();
#pragma unroll
    for (int kk = 0; kk < 16; kk++) {
      float a[4];
#pragma unroll
      for (int i = 0; i < 4; i++) a[i] = As[ty * 4 + i][kk];
      float4 u = *reinterpret_cast<const float4*>(&Bs1[kk][tx * 4]);
      float4 g = *reinterpret_cast<const float4*>(&Bs2[kk][tx * 4]);
#pragma unroll
      for (int i = 0; i < 4; i++) {
        c1[i][0] += a[i] * u.x; c1[i][1] += a[i] * u.y; c1[i][2] += a[i] * u.z; c1[i][3] += a[i] * u.w;
        c2[i][0] += a[i] * g.x; c2[i][1] += a[i] * g.y; c2[i][2] += a[i] * g.z; c2[i][3] += a[i] * g.w;
      }
    }
    __syncthreads();
  }
#pragma unroll
  for (int i = 0; i < 4; i++) {
    if (ty * 4 + i < nv) {
      size_t rowg = (size_t)(base + ty * 4 + i);
#pragma unroll
      for (int j = 0; j < 4; j++) {
        int jj = col0 + tx * 4 + j;
        float z1 = c1[i][j] + b1f[e * FF + jj];
        float zg = c2[i][j] + bgf[e * FF + jj];
        float sl = z1 / (1.f + expf(-z1));
        hbuf[rowg * FF + jj] = sl * zg;
      }
    }
  }
}

// ---------------- MoE down-projection: y = h@W2 + b2 ----------------
__global__ __launch_bounds__(256) void k_ff2(
    const float* __restrict__ hbuf,
    const int* __restrict__ te, const int* __restrict__ tbase, const int* __restrict__ tnv,
    const float* __restrict__ W2, const float* __restrict__ b2f,
    float* __restrict__ ybuf) {
  const int mt = blockIdx.x;
  const int e = te[mt];
  if (e < 0) return;
  const int base = tbase[mt], nv = tnv[mt];
  const int col0 = blockIdx.y * 64;
  const float* W2e = W2 + (size_t)e * FF * D;
  __shared__ float As[64][17];
  __shared__ float Bs[16][68];
  const int tid = threadIdx.x, ty = tid >> 4, tx = tid & 15;
  float acc[4][4] = {};
  const int ar = tid >> 2, ak = (tid & 3) * 4;
  const int bkk = tid >> 4, bj = (tid & 15) * 4;
  for (int k0 = 0; k0 < FF; k0 += 16) {
    float4 a4 = *reinterpret_cast<const float4*>(hbuf + (size_t)(base + ar) * FF + k0 + ak);
    float4 b4 = *reinterpret_cast<const float4*>(W2e + (size_t)(k0 + bkk) * D + col0 + bj);
    As[ar][ak] = a4.x; As[ar][ak + 1] = a4.y; As[ar][ak + 2] = a4.z; As[ar][ak + 3] = a4.w;
    *reinterpret_cast<float4*>(&Bs[bkk][bj]) = b4;
    __syncthreads();
#pragma unroll
    for (int kk = 0; kk < 16; kk++) {
      float a[4];
#pragma unroll
      for (int i = 0; i < 4; i++) a[i] = As[ty * 4 + i][kk];
      float4 b = *reinterpret_cast<const float4*>(&Bs[kk][tx * 4]);
#pragma unroll
      for (int i = 0; i < 4; i++) {
        acc[i][0] += a[i] * b.x; acc[i][1] += a[i] * b.y;
        acc[i][2] += a[i] * b.z; acc[i][3] += a[i] * b.w;
      }
    }
    __syncthreads();
  }
#pragma unroll
  for (int i = 0; i < 4; i++) {
    if (ty * 4 + i < nv) {
      size_t rowg = (size_t)(base + ty * 4 + i);
#pragma unroll
      for (int j = 0; j < 4; j++) {
        int jj = col0 + tx * 4 + j;
        ybuf[rowg * D + jj] = acc[i][j] + b2f[e * D + jj];
      }
    }
  }
}

// ---------------- moe-sum + residual + LN2 ----------------
__global__ __launch_bounds__(256) void k_ln2(
    const float* __restrict__ ybuf, const int* __restrict__ tokpos,
    const float* __restrict__ norm, const float* __restrict__ s2, const float* __restrict__ b2,
    float* __restrict__ out) {
  const int n = blockIdx.x, t = threadIdx.x;
  __shared__ float red[256];
  int p0 = tokpos[n * 2 + 0], p1 = tokpos[n * 2 + 1];
  float val = ybuf[(size_t)p0 * D + t] + ybuf[(size_t)p1 * D + t] + norm[(size_t)n * D + t];
  red[t] = val; __syncthreads();
  for (int s = 128; s > 0; s >>= 1) { if (t < s) red[t] += red[t + s]; __syncthreads(); }
  float m = red[0] * (1.f / D); __syncthreads();
  float df = val - m;
  red[t] = df * df; __syncthreads();
  for (int s = 128; s > 0; s >>= 1) { if (t < s) red[t] += red[t + s]; __syncthreads(); }
  float rstd = rsqrtf(red[0] * (1.f / D) + EPS);
  out[(size_t)n * D + t] = df * rstd * s2[t] + b2[t];
}

extern "C" void kernel_launch(void* const* d_in, const int* in_sizes, int n_in,
                              void* d_out, int out_size, void* d_ws, size_t ws_size,
                              hipStream_t stream) {
  (void)in_sizes; (void)n_in; (void)out_size; (void)ws_size;
  const int*   tok = (const int*)d_in[0];
  const float* emb = (const float*)d_in[1];
  const float* Wq  = (const float*)d_in[2];
  const float* bq  = (const float*)d_in[3];
  const float* Wk  = (const float*)d_in[4];
  const float* bk  = (const float*)d_in[5];
  const float* Wv  = (const float*)d_in[6];
  const float* bv  = (const float*)d_in[7];
  const float* l1s = (const float*)d_in[8];
  const float* l1b = (const float*)d_in[9];
  const float* l2s = (const float*)d_in[10];
  const float* l2b = (const float*)d_in[11];
  const float* gW  = (const float*)d_in[12];
  const float* gb  = (const float*)d_in[13];
  const float* f1W = (const float*)d_in[14];
  const float* f1b = (const float*)d_in[15];
  const float* fgW = (const float*)d_in[16];
  const float* fgb = (const float*)d_in[17];
  const float* f2W = (const float*)d_in[18];
  const float* f2b = (const float*)d_in[19];
  float* out = (float*)d_out;

  char* p = (char*)d_ws;
  auto alloc = [&](size_t bytes) { char* r = p; p += (bytes + 255) & ~(size_t)255; return r; };
  float* xb = (float*)alloc((size_t)NT * D * 4);
  float* qb = (float*)alloc((size_t)NT * D * 4);
  float* kb = (float*)alloc((size_t)NT * D * 4);
  float* vb = (float*)alloc((size_t)NT * D * 4);
  float* ob = (float*)alloc((size_t)NT * D * 4);
  float* nb = (float*)alloc((size_t)NT * D * 4);
  float* hb = (float*)alloc((size_t)PADROWS * FF * 4);
  float* yb = (float*)alloc((size_t)PADROWS * D * 4);
  int* eidx   = (int*)alloc((size_t)NT * 2 * 4);
  int* rlist  = (int*)alloc((size_t)PADROWS * 4);
  int* tokpos = (int*)alloc((size_t)NT * 2 * 4);
  int* te     = (int*)alloc(MAXT * 4);
  int* tbase  = (int*)alloc(MAXT * 4);
  int* tnv    = (int*)alloc(MAXT * 4);

  k_embed<<<NT, 256, 0, stream>>>(tok, emb, xb);

  for (int l = 0; l < LNUM; l++) {
    k_qkv<<<dim3(32, 4, 3), 256, 0, stream>>>(
        xb,
        Wq + (size_t)l * D * D, bq + (size_t)l * D,
        Wk + (size_t)l * D * D, bk + (size_t)l * D,
        Wv + (size_t)l * D * D, bv + (size_t)l * D,
        qb, kb, vb);
    k_attn<<<dim3(8, 32), 256, 0, stream>>>(qb, kb, vb, ob);
    k_ln1gate<<<NT, 256, 0, stream>>>(ob, xb, l1s + (size_t)l * D, l1b + (size_t)l * D,
                                      gW + (size_t)l * D * NE, gb + (size_t)l * NE, nb, eidx);
    k_route<<<1, 256, 0, stream>>>(eidx, rlist, tokpos, te, tbase, tnv);
    k_ff1<<<dim3(75, 8), 256, 0, stream>>>(
        nb, rlist, te, tbase, tnv,
        f1W + (size_t)l * NE * D * FF, f1b + (size_t)l * NE * FF,
        fgW + (size_t)l * NE * D * FF, fgb + (size_t)l * NE * FF, hb);
    k_ff2<<<dim3(75, 4), 256, 0, stream>>>(
        hb, te, tbase, tnv,
        f2W + (size_t)l * NE * FF * D, f2b + (size_t)l * NE * D, yb);
    k_ln2<<<NT, 256, 0, stream>>>(yb, tokpos, nb, l2s + (size_t)l * D, l2b + (size_t)l * D,
                                  (l == LNUM - 1) ? out : xb);
  }
}

// Round 3
// 2523.380 us; speedup vs baseline: 1.1715x; 1.1715x over previous
//
#include <hip/hip_runtime.h>
#include <math.h>

#define LNUM 16
#define D 256
#define FF 512
#define NH 8
#define NE 12
#define HD 32
#define BB 4
#define SS 512
#define NT 2048      // B*S
#define EPS 1e-5f
#define MAXT 80
#define PADROWS 4864

typedef _Float16 f16;
typedef __attribute__((ext_vector_type(8))) _Float16 f16x8;
typedef __attribute__((ext_vector_type(4))) float f32x4;
#define MFMA(A, B, C) __builtin_amdgcn_mfma_f32_16x16x32_f16((A), (B), (C), 0, 0, 0)

__device__ inline void splitf(float x, f16& h, f16& l) {
  f16 hh = (f16)x;
  h = hh;
  l = (f16)(x - (float)hh);
}

// split 8 floats (two float4) into hi/lo f16x8 vectors
__device__ inline void split8(float4 a0, float4 a1, f16x8& hv, f16x8& lv) {
  f16 h[8], l[8];
  splitf(a0.x, h[0], l[0]); splitf(a0.y, h[1], l[1]);
  splitf(a0.z, h[2], l[2]); splitf(a0.w, h[3], l[3]);
  splitf(a1.x, h[4], l[4]); splitf(a1.y, h[5], l[5]);
  splitf(a1.z, h[6], l[6]); splitf(a1.w, h[7], l[7]);
#pragma unroll
  for (int j = 0; j < 8; j++) { hv[j] = h[j]; lv[j] = l[j]; }
}

// ---------------- embedding gather ----------------
__global__ __launch_bounds__(256) void k_embed(const int* __restrict__ tok,
                                               const float* __restrict__ emb,
                                               float* __restrict__ x) {
  int n = blockIdx.x, t = threadIdx.x;
  x[(size_t)n * D + t] = emb[(size_t)tok[n] * D + t];
}

// ---------------- QKV projection via fp16x3 MFMA ----------------
// grid (32 row-tiles, 4 col-tiles, 3 mats), 256 thr
__global__ __launch_bounds__(256) void k_qkv_mfma(
    const float* __restrict__ x,
    const float* __restrict__ Wq, const float* __restrict__ bq,
    const float* __restrict__ Wk, const float* __restrict__ bk,
    const float* __restrict__ Wv, const float* __restrict__ bv,
    float* __restrict__ qo, float* __restrict__ ko, float* __restrict__ vo) {
  const float* W; const float* bias; float* out;
  if (blockIdx.z == 0)      { W = Wq; bias = bq; out = qo; }
  else if (blockIdx.z == 1) { W = Wk; bias = bk; out = ko; }
  else                      { W = Wv; bias = bv; out = vo; }
  const int row0 = blockIdx.x * 64, col0 = blockIdx.y * 64;
  __shared__ f16 Ah[64][40], Al[64][40], Bh[64][40], Bl[64][40];
  const int tid = threadIdx.x;
  const int ar = tid >> 2, ac = (tid & 3) * 8;     // A stage: 64 rows x 32 k
  const int bk2 = tid >> 3, bn = (tid & 7) * 8;    // B stage: 32 k x 64 n
  const int lane = tid & 63, w = tid >> 6;
  const int wr = w >> 1, wc = w & 1;
  const int lm = lane & 15, lk = (lane >> 4) * 8;
  f32x4 acc[2][2] = {};
  for (int k0 = 0; k0 < D; k0 += 32) {
    {
      float4 a0 = *reinterpret_cast<const float4*>(x + (size_t)(row0 + ar) * D + k0 + ac);
      float4 a1 = *reinterpret_cast<const float4*>(x + (size_t)(row0 + ar) * D + k0 + ac + 4);
      f16x8 h, l;
      split8(a0, a1, h, l);
      *reinterpret_cast<f16x8*>(&Ah[ar][ac]) = h;
      *reinterpret_cast<f16x8*>(&Al[ar][ac]) = l;
      float4 b0 = *reinterpret_cast<const float4*>(W + (size_t)(k0 + bk2) * D + col0 + bn);
      float4 b1 = *reinterpret_cast<const float4*>(W + (size_t)(k0 + bk2) * D + col0 + bn + 4);
      f16 bh[8], bl[8];
      splitf(b0.x, bh[0], bl[0]); splitf(b0.y, bh[1], bl[1]);
      splitf(b0.z, bh[2], bl[2]); splitf(b0.w, bh[3], bl[3]);
      splitf(b1.x, bh[4], bl[4]); splitf(b1.y, bh[5], bl[5]);
      splitf(b1.z, bh[6], bl[6]); splitf(b1.w, bh[7], bl[7]);
#pragma unroll
      for (int j = 0; j < 8; j++) { Bh[bn + j][bk2] = bh[j]; Bl[bn + j][bk2] = bl[j]; }
    }
    __syncthreads();
    f16x8 a_h[2], a_l[2], b_h[2], b_l[2];
#pragma unroll
    for (int mt = 0; mt < 2; mt++) {
      a_h[mt] = *reinterpret_cast<const f16x8*>(&Ah[wr * 32 + mt * 16 + lm][lk]);
      a_l[mt] = *reinterpret_cast<const f16x8*>(&Al[wr * 32 + mt * 16 + lm][lk]);
    }
#pragma unroll
    for (int nt = 0; nt < 2; nt++) {
      b_h[nt] = *reinterpret_cast<const f16x8*>(&Bh[wc * 32 + nt * 16 + lm][lk]);
      b_l[nt] = *reinterpret_cast<const f16x8*>(&Bl[wc * 32 + nt * 16 + lm][lk]);
    }
#pragma unroll
    for (int mt = 0; mt < 2; mt++)
#pragma unroll
      for (int nt = 0; nt < 2; nt++) {
        f32x4 c = acc[mt][nt];
        c = MFMA(a_h[mt], b_h[nt], c);
        c = MFMA(a_h[mt], b_l[nt], c);
        c = MFMA(a_l[mt], b_h[nt], c);
        acc[mt][nt] = c;
      }
    __syncthreads();
  }
#pragma unroll
  for (int mt = 0; mt < 2; mt++)
#pragma unroll
    for (int nt = 0; nt < 2; nt++) {
      int col = col0 + wc * 32 + nt * 16 + lm;
#pragma unroll
      for (int r = 0; r < 4; r++) {
        int row = row0 + wr * 32 + mt * 16 + (lane >> 4) * 4 + r;
        out[(size_t)row * D + col] = acc[mt][nt][r] + bias[col];
      }
    }
}

// ---------------- flash-style fp32 causal attention (no 1/sqrt(d) scale, per reference) ----------------
__global__ __launch_bounds__(256) void k_attn(const float* __restrict__ q,
                                              const float* __restrict__ k,
                                              const float* __restrict__ v,
                                              float* __restrict__ o) {
  const int rt = blockIdx.x, bh = blockIdx.y;
  const int b = bh >> 3, h = bh & 7;
  const int row0 = rt * 64;
  __shared__ float Qs[64][33], Ks[64][33], Vs[64][33], Ps[64][68];
  const int tid = threadIdx.x, ty = tid >> 4, tx = tid & 15;
  const int lr = tid >> 2, lw = (tid & 3) * 8;
  {
    const float* qp = q + (size_t)(b * SS + row0 + lr) * D + h * HD + lw;
    float4 q0 = *reinterpret_cast<const float4*>(qp);
    float4 q1 = *reinterpret_cast<const float4*>(qp + 4);
    Qs[lr][lw + 0] = q0.x; Qs[lr][lw + 1] = q0.y; Qs[lr][lw + 2] = q0.z; Qs[lr][lw + 3] = q0.w;
    Qs[lr][lw + 4] = q1.x; Qs[lr][lw + 5] = q1.y; Qs[lr][lw + 6] = q1.z; Qs[lr][lw + 7] = q1.w;
  }
  float oacc[4][2] = {};
  float mrow[4], lsum[4];
#pragma unroll
  for (int i = 0; i < 4; i++) { mrow[i] = -1e30f; lsum[i] = 0.f; }

  for (int ct = 0; ct <= rt; ct++) {
    __syncthreads();
    {
      const float* kp = k + (size_t)(b * SS + ct * 64 + lr) * D + h * HD + lw;
      const float* vp = v + (size_t)(b * SS + ct * 64 + lr) * D + h * HD + lw;
      float4 k0 = *reinterpret_cast<const float4*>(kp);
      float4 k1 = *reinterpret_cast<const float4*>(kp + 4);
      float4 v0 = *reinterpret_cast<const float4*>(vp);
      float4 v1 = *reinterpret_cast<const float4*>(vp + 4);
      Ks[lr][lw + 0] = k0.x; Ks[lr][lw + 1] = k0.y; Ks[lr][lw + 2] = k0.z; Ks[lr][lw + 3] = k0.w;
      Ks[lr][lw + 4] = k1.x; Ks[lr][lw + 5] = k1.y; Ks[lr][lw + 6] = k1.z; Ks[lr][lw + 7] = k1.w;
      Vs[lr][lw + 0] = v0.x; Vs[lr][lw + 1] = v0.y; Vs[lr][lw + 2] = v0.z; Vs[lr][lw + 3] = v0.w;
      Vs[lr][lw + 4] = v1.x; Vs[lr][lw + 5] = v1.y; Vs[lr][lw + 6] = v1.z; Vs[lr][lw + 7] = v1.w;
    }
    __syncthreads();
    float sc[4][4] = {};
#pragma unroll
    for (int w = 0; w < HD; w++) {
      float a[4], bb2[4];
#pragma unroll
      for (int i = 0; i < 4; i++) a[i] = Qs[ty * 4 + i][w];
#pragma unroll
      for (int j = 0; j < 4; j++) bb2[j] = Ks[tx * 4 + j][w];
#pragma unroll
      for (int i = 0; i < 4; i++)
#pragma unroll
        for (int j = 0; j < 4; j++) sc[i][j] += a[i] * bb2[j];
    }
    if (ct == rt) {
#pragma unroll
      for (int i = 0; i < 4; i++)
#pragma unroll
        for (int j = 0; j < 4; j++)
          if (tx * 4 + j > ty * 4 + i) sc[i][j] = -1e30f;
    }
#pragma unroll
    for (int i = 0; i < 4; i++) {
      float mt = fmaxf(fmaxf(sc[i][0], sc[i][1]), fmaxf(sc[i][2], sc[i][3]));
      for (int msk = 1; msk < 16; msk <<= 1) mt = fmaxf(mt, __shfl_xor(mt, msk, 16));
      float mn = fmaxf(mrow[i], mt);
      float scal = expf(mrow[i] - mn);
      float p0 = expf(sc[i][0] - mn), p1 = expf(sc[i][1] - mn);
      float p2 = expf(sc[i][2] - mn), p3 = expf(sc[i][3] - mn);
      float rs = p0 + p1 + p2 + p3;
      for (int msk = 1; msk < 16; msk <<= 1) rs += __shfl_xor(rs, msk, 16);
      lsum[i] = lsum[i] * scal + rs;
      mrow[i] = mn;
      oacc[i][0] *= scal; oacc[i][1] *= scal;
      Ps[ty * 4 + i][tx * 4 + 0] = p0;
      Ps[ty * 4 + i][tx * 4 + 1] = p1;
      Ps[ty * 4 + i][tx * 4 + 2] = p2;
      Ps[ty * 4 + i][tx * 4 + 3] = p3;
    }
    __syncthreads();
#pragma unroll 8
    for (int t2 = 0; t2 < 64; t2++) {
      float v0 = Vs[t2][tx * 2], v1 = Vs[t2][tx * 2 + 1];
#pragma unroll
      for (int i = 0; i < 4; i++) {
        float pp = Ps[ty * 4 + i][t2];
        oacc[i][0] += pp * v0; oacc[i][1] += pp * v1;
      }
    }
  }
#pragma unroll
  for (int i = 0; i < 4; i++) {
    float inv = 1.f / lsum[i];
    size_t base = (size_t)(b * SS + row0 + ty * 4 + i) * D + h * HD + tx * 2;
    o[base + 0] = oacc[i][0] * inv;
    o[base + 1] = oacc[i][1] * inv;
  }
}

// ---------------- residual + LN1 + gate logits + top-2 ----------------
__global__ __launch_bounds__(256) void k_ln1gate(
    const float* __restrict__ o, const float* __restrict__ x,
    const float* __restrict__ s1, const float* __restrict__ b1,
    const float* __restrict__ gW, const float* __restrict__ gb,
    float* __restrict__ norm, int* __restrict__ eidx) {
  const int n = blockIdx.x, t = threadIdx.x;
  __shared__ float red[256];
  __shared__ float gl[NE];
  float val = o[(size_t)n * D + t] + x[(size_t)n * D + t];
  red[t] = val; __syncthreads();
  for (int s = 128; s > 0; s >>= 1) { if (t < s) red[t] += red[t + s]; __syncthreads(); }
  float m = red[0] * (1.f / D); __syncthreads();
  float df = val - m;
  red[t] = df * df; __syncthreads();
  for (int s = 128; s > 0; s >>= 1) { if (t < s) red[t] += red[t + s]; __syncthreads(); }
  float rstd = rsqrtf(red[0] * (1.f / D) + EPS); __syncthreads();
  float nv = df * rstd * s1[t] + b1[t];
  norm[(size_t)n * D + t] = nv;
  red[t] = nv; __syncthreads();
  if (t < NE) {
    float acc = gb[t];
    for (int d2 = 0; d2 < D; d2++) acc += red[d2] * gW[d2 * NE + t];
    gl[t] = acc;
  }
  __syncthreads();
  if (t == 0) {
    int i1 = 0; float v1 = gl[0];
    for (int e = 1; e < NE; e++) if (gl[e] > v1) { v1 = gl[e]; i1 = e; }
    int i2 = -1; float v2 = -3.4e38f;
    for (int e = 0; e < NE; e++) if (e != i1 && gl[e] > v2) { v2 = gl[e]; i2 = e; }
    eidx[n * 2 + 0] = i1;
    eidx[n * 2 + 1] = i2;
  }
}

// ---------------- routing: counts -> padded tiles -> scatter ----------------
__global__ __launch_bounds__(256) void k_route(const int* __restrict__ eidx,
                                               int* __restrict__ rlist, int* __restrict__ tokpos,
                                               int* __restrict__ te, int* __restrict__ tbase,
                                               int* __restrict__ tnv) {
  __shared__ int cnt[NE], cur[NE], poff[NE];
  const int t = threadIdx.x;
  if (t < NE) { cnt[t] = 0; cur[t] = 0; }
  __syncthreads();
  for (int n = t; n < NT; n += 256) {
    atomicAdd(&cnt[eidx[n * 2 + 0]], 1);
    atomicAdd(&cnt[eidx[n * 2 + 1]], 1);
  }
  __syncthreads();
  if (t == 0) {
    int off = 0, ti = 0;
    for (int e = 0; e < NE; e++) {
      poff[e] = off;
      int nt = (cnt[e] + 63) >> 6;
      for (int tt = 0; tt < nt; tt++) {
        te[ti] = e; tbase[ti] = off + tt * 64;
        int rem = cnt[e] - tt * 64; tnv[ti] = rem < 64 ? rem : 64;
        ti++;
      }
      off += nt * 64;
    }
    for (; ti < MAXT; ti++) te[ti] = -1;
  }
  __syncthreads();
  for (int n = t; n < NT; n += 256) {
#pragma unroll
    for (int s2 = 0; s2 < 2; s2++) {
      int e = eidx[n * 2 + s2];
      int pos = atomicAdd(&cur[e], 1);
      int row = poff[e] + pos;
      rlist[row] = n;
      tokpos[n * 2 + s2] = row;
    }
  }
}

// ---------------- MoE up-projection via fp16x3 MFMA: h = silu(norm@W1+b1)*(norm@Wg+bg) ----------------
// grid (75 row-tiles, 8 col-tiles), 256 thr
__global__ __launch_bounds__(256) void k_ff1_mfma(
    const float* __restrict__ norm, const int* __restrict__ rlist,
    const int* __restrict__ te, const int* __restrict__ tbase, const int* __restrict__ tnv,
    const float* __restrict__ W1, const float* __restrict__ b1f,
    const float* __restrict__ Wg, const float* __restrict__ bgf,
    float* __restrict__ hbuf) {
  const int mt0 = blockIdx.x;
  const int e = te[mt0];
  if (e < 0) return;
  const int base = tbase[mt0], nv = tnv[mt0];
  const int col0 = blockIdx.y * 64;
  const float* W1e = W1 + (size_t)e * D * FF;
  const float* Wge = Wg + (size_t)e * D * FF;
  __shared__ f16 Ah[64][40], Al[64][40];
  __shared__ f16 B1h[64][40], B1l[64][40], B2h[64][40], B2l[64][40];
  __shared__ int rows[64];
  const int tid = threadIdx.x;
  if (tid < 64) rows[tid] = (tid < nv) ? rlist[base + tid] : 0;
  __syncthreads();
  const int ar = tid >> 2, ac = (tid & 3) * 8;
  const int bk2 = tid >> 3, bn = (tid & 7) * 8;
  const int lane = tid & 63, w = tid >> 6;
  const int wr = w >> 1, wc = w & 1;
  const int lm = lane & 15, lk = (lane >> 4) * 8;
  f32x4 acc1[2][2] = {}, acc2[2][2] = {};
  for (int k0 = 0; k0 < D; k0 += 32) {
    {
      const float* ap = norm + (size_t)rows[ar] * D + k0 + ac;
      float4 a0 = *reinterpret_cast<const float4*>(ap);
      float4 a1 = *reinterpret_cast<const float4*>(ap + 4);
      f16x8 h, l;
      split8(a0, a1, h, l);
      *reinterpret_cast<f16x8*>(&Ah[ar][ac]) = h;
      *reinterpret_cast<f16x8*>(&Al[ar][ac]) = l;
      const float* b1p = W1e + (size_t)(k0 + bk2) * FF + col0 + bn;
      const float* b2p = Wge + (size_t)(k0 + bk2) * FF + col0 + bn;
      float4 u0 = *reinterpret_cast<const float4*>(b1p);
      float4 u1 = *reinterpret_cast<const float4*>(b1p + 4);
      float4 g0 = *reinterpret_cast<const float4*>(b2p);
      float4 g1 = *reinterpret_cast<const float4*>(b2p + 4);
      f16 bh[8], bl[8], ch[8], cl[8];
      splitf(u0.x, bh[0], bl[0]); splitf(u0.y, bh[1], bl[1]);
      splitf(u0.z, bh[2], bl[2]); splitf(u0.w, bh[3], bl[3]);
      splitf(u1.x, bh[4], bl[4]); splitf(u1.y, bh[5], bl[5]);
      splitf(u1.z, bh[6], bl[6]); splitf(u1.w, bh[7], bl[7]);
      splitf(g0.x, ch[0], cl[0]); splitf(g0.y, ch[1], cl[1]);
      splitf(g0.z, ch[2], cl[2]); splitf(g0.w, ch[3], cl[3]);
      splitf(g1.x, ch[4], cl[4]); splitf(g1.y, ch[5], cl[5]);
      splitf(g1.z, ch[6], cl[6]); splitf(g1.w, ch[7], cl[7]);
#pragma unroll
      for (int j = 0; j < 8; j++) {
        B1h[bn + j][bk2] = bh[j]; B1l[bn + j][bk2] = bl[j];
        B2h[bn + j][bk2] = ch[j]; B2l[bn + j][bk2] = cl[j];
      }
    }
    __syncthreads();
    f16x8 a_h[2], a_l[2];
#pragma unroll
    for (int mt = 0; mt < 2; mt++) {
      a_h[mt] = *reinterpret_cast<const f16x8*>(&Ah[wr * 32 + mt * 16 + lm][lk]);
      a_l[mt] = *reinterpret_cast<const f16x8*>(&Al[wr * 32 + mt * 16 + lm][lk]);
    }
#pragma unroll
    for (int nt = 0; nt < 2; nt++) {
      f16x8 b_h = *reinterpret_cast<const f16x8*>(&B1h[wc * 32 + nt * 16 + lm][lk]);
      f16x8 b_l = *reinterpret_cast<const f16x8*>(&B1l[wc * 32 + nt * 16 + lm][lk]);
      f16x8 c_h = *reinterpret_cast<const f16x8*>(&B2h[wc * 32 + nt * 16 + lm][lk]);
      f16x8 c_l = *reinterpret_cast<const f16x8*>(&B2l[wc * 32 + nt * 16 + lm][lk]);
#pragma unroll
      for (int mt = 0; mt < 2; mt++) {
        f32x4 c1 = acc1[mt][nt];
        c1 = MFMA(a_h[mt], b_h, c1);
        c1 = MFMA(a_h[mt], b_l, c1);
        c1 = MFMA(a_l[mt], b_h, c1);
        acc1[mt][nt] = c1;
        f32x4 c2 = acc2[mt][nt];
        c2 = MFMA(a_h[mt], c_h, c2);
        c2 = MFMA(a_h[mt], c_l, c2);
        c2 = MFMA(a_l[mt], c_h, c2);
        acc2[mt][nt] = c2;
      }
    }
    __syncthreads();
  }
#pragma unroll
  for (int mt = 0; mt < 2; mt++)
#pragma unroll
    for (int nt = 0; nt < 2; nt++) {
      int col = col0 + wc * 32 + nt * 16 + lm;
      float bb1 = b1f[e * FF + col], bb2 = bgf[e * FF + col];
#pragma unroll
      for (int r = 0; r < 4; r++) {
        int rit = wr * 32 + mt * 16 + (lane >> 4) * 4 + r;
        if (rit < nv) {
          float z1 = acc1[mt][nt][r] + bb1;
          float zg = acc2[mt][nt][r] + bb2;
          float sl = z1 / (1.f + expf(-z1));
          hbuf[(size_t)(base + rit) * FF + col] = sl * zg;
        }
      }
    }
}

// ---------------- MoE down-projection via fp16x3 MFMA: y = h@W2 + b2 ----------------
// grid (75 row-tiles, 4 col-tiles), 256 thr
__global__ __launch_bounds__(256) void k_ff2_mfma(
    const float* __restrict__ hbuf,
    const int* __restrict__ te, const int* __restrict__ tbase, const int* __restrict__ tnv,
    const float* __restrict__ W2, const float* __restrict__ b2f,
    float* __restrict__ ybuf) {
  const int mt0 = blockIdx.x;
  const int e = te[mt0];
  if (e < 0) return;
  const int base = tbase[mt0], nv = tnv[mt0];
  const int col0 = blockIdx.y * 64;
  const float* W2e = W2 + (size_t)e * FF * D;
  __shared__ f16 Ah[64][40], Al[64][40], Bh[64][40], Bl[64][40];
  const int tid = threadIdx.x;
  const int ar = tid >> 2, ac = (tid & 3) * 8;
  const int bk2 = tid >> 3, bn = (tid & 7) * 8;
  const int lane = tid & 63, w = tid >> 6;
  const int wr = w >> 1, wc = w & 1;
  const int lm = lane & 15, lk = (lane >> 4) * 8;
  f32x4 acc[2][2] = {};
  for (int k0 = 0; k0 < FF; k0 += 32) {
    {
      const float* ap = hbuf + (size_t)(base + ar) * FF + k0 + ac;
      float4 a0 = *reinterpret_cast<const float4*>(ap);
      float4 a1 = *reinterpret_cast<const float4*>(ap + 4);
      f16x8 h, l;
      split8(a0, a1, h, l);
      *reinterpret_cast<f16x8*>(&Ah[ar][ac]) = h;
      *reinterpret_cast<f16x8*>(&Al[ar][ac]) = l;
      const float* bp = W2e + (size_t)(k0 + bk2) * D + col0 + bn;
      float4 b0 = *reinterpret_cast<const float4*>(bp);
      float4 b1 = *reinterpret_cast<const float4*>(bp + 4);
      f16 bh[8], bl[8];
      splitf(b0.x, bh[0], bl[0]); splitf(b0.y, bh[1], bl[1]);
      splitf(b0.z, bh[2], bl[2]); splitf(b0.w, bh[3], bl[3]);
      splitf(b1.x, bh[4], bl[4]); splitf(b1.y, bh[5], bl[5]);
      splitf(b1.z, bh[6], bl[6]); splitf(b1.w, bh[7], bl[7]);
#pragma unroll
      for (int j = 0; j < 8; j++) { Bh[bn + j][bk2] = bh[j]; Bl[bn + j][bk2] = bl[j]; }
    }
    __syncthreads();
    f16x8 a_h[2], a_l[2], b_h[2], b_l[2];
#pragma unroll
    for (int mt = 0; mt < 2; mt++) {
      a_h[mt] = *reinterpret_cast<const f16x8*>(&Ah[wr * 32 + mt * 16 + lm][lk]);
      a_l[mt] = *reinterpret_cast<const f16x8*>(&Al[wr * 32 + mt * 16 + lm][lk]);
    }
#pragma unroll
    for (int nt = 0; nt < 2; nt++) {
      b_h[nt] = *reinterpret_cast<const f16x8*>(&Bh[wc * 32 + nt * 16 + lm][lk]);
      b_l[nt] = *reinterpret_cast<const f16x8*>(&Bl[wc * 32 + nt * 16 + lm][lk]);
    }
#pragma unroll
    for (int mt = 0; mt < 2; mt++)
#pragma unroll
      for (int nt = 0; nt < 2; nt++) {
        f32x4 c = acc[mt][nt];
        c = MFMA(a_h[mt], b_h[nt], c);
        c = MFMA(a_h[mt], b_l[nt], c);
        c = MFMA(a_l[mt], b_h[nt], c);
        acc[mt][nt] = c;
      }
    __syncthreads();
  }
#pragma unroll
  for (int mt = 0; mt < 2; mt++)
#pragma unroll
    for (int nt = 0; nt < 2; nt++) {
      int col = col0 + wc * 32 + nt * 16 + lm;
      float bb = b2f[e * D + col];
#pragma unroll
      for (int r = 0; r < 4; r++) {
        int rit = wr * 32 + mt * 16 + (lane >> 4) * 4 + r;
        if (rit < nv) ybuf[(size_t)(base + rit) * D + col] = acc[mt][nt][r] + bb;
      }
    }
}

// ---------------- moe-sum + residual + LN2 ----------------
__global__ __launch_bounds__(256) void k_ln2(
    const float* __restrict__ ybuf, const int* __restrict__ tokpos,
    const float* __restrict__ norm, const float* __restrict__ s2, const float* __restrict__ b2,
    float* __restrict__ out) {
  const int n = blockIdx.x, t = threadIdx.x;
  __shared__ float red[256];
  int p0 = tokpos[n * 2 + 0], p1 = tokpos[n * 2 + 1];
  float val = ybuf[(size_t)p0 * D + t] + ybuf[(size_t)p1 * D + t] + norm[(size_t)n * D + t];
  red[t] = val; __syncthreads();
  for (int s = 128; s > 0; s >>= 1) { if (t < s) red[t] += red[t + s]; __syncthreads(); }
  float m = red[0] * (1.f / D); __syncthreads();
  float df = val - m;
  red[t] = df * df; __syncthreads();
  for (int s = 128; s > 0; s >>= 1) { if (t < s) red[t] += red[t + s]; __syncthreads(); }
  float rstd = rsqrtf(red[0] * (1.f / D) + EPS);
  out[(size_t)n * D + t] = df * rstd * s2[t] + b2[t];
}

extern "C" void kernel_launch(void* const* d_in, const int* in_sizes, int n_in,
                              void* d_out, int out_size, void* d_ws, size_t ws_size,
                              hipStream_t stream) {
  (void)in_sizes; (void)n_in; (void)out_size; (void)ws_size;
  const int*   tok = (const int*)d_in[0];
  const float* emb = (const float*)d_in[1];
  const float* Wq  = (const float*)d_in[2];
  const float* bq  = (const float*)d_in[3];
  const float* Wk  = (const float*)d_in[4];
  const float* bk  = (const float*)d_in[5];
  const float* Wv  = (const float*)d_in[6];
  const float* bv  = (const float*)d_in[7];
  const float* l1s = (const float*)d_in[8];
  const float* l1b = (const float*)d_in[9];
  const float* l2s = (const float*)d_in[10];
  const float* l2b = (const float*)d_in[11];
  const float* gW  = (const float*)d_in[12];
  const float* gb  = (const float*)d_in[13];
  const float* f1W = (const float*)d_in[14];
  const float* f1b = (const float*)d_in[15];
  const float* fgW = (const float*)d_in[16];
  const float* fgb = (const float*)d_in[17];
  const float* f2W = (const float*)d_in[18];
  const float* f2b = (const float*)d_in[19];
  float* out = (float*)d_out;

  char* p = (char*)d_ws;
  auto alloc = [&](size_t bytes) { char* r = p; p += (bytes + 255) & ~(size_t)255; return r; };
  float* xb = (float*)alloc((size_t)NT * D * 4);
  float* qb = (float*)alloc((size_t)NT * D * 4);
  float* kb = (float*)alloc((size_t)NT * D * 4);
  float* vb = (float*)alloc((size_t)NT * D * 4);
  float* ob = (float*)alloc((size_t)NT * D * 4);
  float* nb = (float*)alloc((size_t)NT * D * 4);
  float* hb = (float*)alloc((size_t)PADROWS * FF * 4);
  float* yb = (float*)alloc((size_t)PADROWS * D * 4);
  int* eidx   = (int*)alloc((size_t)NT * 2 * 4);
  int* rlist  = (int*)alloc((size_t)PADROWS * 4);
  int* tokpos = (int*)alloc((size_t)NT * 2 * 4);
  int* te     = (int*)alloc(MAXT * 4);
  int* tbase  = (int*)alloc(MAXT * 4);
  int* tnv    = (int*)alloc(MAXT * 4);

  k_embed<<<NT, 256, 0, stream>>>(tok, emb, xb);

  for (int l = 0; l < LNUM; l++) {
    k_qkv_mfma<<<dim3(32, 4, 3), 256, 0, stream>>>(
        xb,
        Wq + (size_t)l * D * D, bq + (size_t)l * D,
        Wk + (size_t)l * D * D, bk + (size_t)l * D,
        Wv + (size_t)l * D * D, bv + (size_t)l * D,
        qb, kb, vb);
    k_attn<<<dim3(8, 32), 256, 0, stream>>>(qb, kb, vb, ob);
    k_ln1gate<<<NT, 256, 0, stream>>>(ob, xb, l1s + (size_t)l * D, l1b + (size_t)l * D,
                                      gW + (size_t)l * D * NE, gb + (size_t)l * NE, nb, eidx);
    k_route<<<1, 256, 0, stream>>>(eidx, rlist, tokpos, te, tbase, tnv);
    k_ff1_mfma<<<dim3(75, 8), 256, 0, stream>>>(
        nb, rlist, te, tbase, tnv,
        f1W + (size_t)l * NE * D * FF, f1b + (size_t)l * NE * FF,
        fgW + (size_t)l * NE * D * FF, fgb + (size_t)l * NE * FF, hb);
    k_ff2_mfma<<<dim3(75, 4), 256, 0, stream>>>(
        hb, te, tbase, tnv,
        f2W + (size_t)l * NE * FF * D, f2b + (size_t)l * NE * D, yb);
    k_ln2<<<NT, 256, 0, stream>>>(yb, tokpos, nb, l2s + (size_t)l * D, l2b + (size_t)l * D,
                                  (l == LNUM - 1) ? out : xb);
  }
}

// Round 4
// 2023.580 us; speedup vs baseline: 1.4608x; 1.2470x over previous
//
#include <hip/hip_runtime.h>
#include <math.h>

#define LNUM 16
#define D 256
#define FF 512
#define NH 8
#define NE 12
#define HD 32
#define BB 4
#define SS 512
#define NT 2048      // B*S
#define EPS 1e-5f
#define MAXT 48
#define PADROWS 5632

typedef _Float16 f16;
typedef __attribute__((ext_vector_type(8))) _Float16 f16x8;
typedef __attribute__((ext_vector_type(4))) float f32x4;
#define MFMA(A, B, C) __builtin_amdgcn_mfma_f32_16x16x32_f16((A), (B), (C), 0, 0, 0)

__device__ inline void splitf(float x, f16& h, f16& l) {
  f16 hh = (f16)x;
  h = hh;
  l = (f16)(x - (float)hh);
}

// ---------------- embedding gather + split ----------------
__global__ __launch_bounds__(256) void k_embed(const int* __restrict__ tok,
                                               const float* __restrict__ emb,
                                               float* __restrict__ x,
                                               f16* __restrict__ xh, f16* __restrict__ xl) {
  int n = blockIdx.x, t = threadIdx.x;
  float val = emb[(size_t)tok[n] * D + t];
  x[(size_t)n * D + t] = val;
  f16 h, l; splitf(val, h, l);
  xh[(size_t)n * D + t] = h;
  xl[(size_t)n * D + t] = l;
}

// ---------------- QKV projection via fp16x3 MFMA, 128x64 tiles ----------------
// grid (16 row-tiles, 4 col-tiles, 3 mats), 256 thr
__global__ __launch_bounds__(256) void k_qkv_mfma(
    const f16* __restrict__ xh, const f16* __restrict__ xl,
    const float* __restrict__ Wq, const float* __restrict__ bq,
    const float* __restrict__ Wk, const float* __restrict__ bk,
    const float* __restrict__ Wv, const float* __restrict__ bv,
    f16* __restrict__ qhb, f16* __restrict__ qlb,
    f16* __restrict__ khb, f16* __restrict__ klb,
    f16* __restrict__ vhb, f16* __restrict__ vlb) {
  const float* W; const float* bias; f16* outh; f16* outl;
  if (blockIdx.z == 0)      { W = Wq; bias = bq; outh = qhb; outl = qlb; }
  else if (blockIdx.z == 1) { W = Wk; bias = bk; outh = khb; outl = klb; }
  else                      { W = Wv; bias = bv; outh = vhb; outl = vlb; }
  const int row0 = blockIdx.x * 128, col0 = blockIdx.y * 64;
  __shared__ f16 Ah[128][40], Al[128][40], Bh[64][40], Bl[64][40];
  const int tid = threadIdx.x;
  const int asr = tid >> 1, asc = (tid & 1) * 16;
  const int bk2 = tid >> 3, bn = (tid & 7) * 8;
  const int lane = tid & 63, w = tid >> 6;
  const int lm = lane & 15, lg = lane >> 4, lk = lg * 8;
  f32x4 acc[2][4] = {};
  for (int k0 = 0; k0 < D; k0 += 32) {
    {
      size_t ga = (size_t)(row0 + asr) * D + k0 + asc;
      *(f16x8*)&Ah[asr][asc]     = *(const f16x8*)(xh + ga);
      *(f16x8*)&Ah[asr][asc + 8] = *(const f16x8*)(xh + ga + 8);
      *(f16x8*)&Al[asr][asc]     = *(const f16x8*)(xl + ga);
      *(f16x8*)&Al[asr][asc + 8] = *(const f16x8*)(xl + ga + 8);
      const float* bp = W + (size_t)(k0 + bk2) * D + col0 + bn;
      float4 b0 = *(const float4*)bp;
      float4 b1 = *(const float4*)(bp + 4);
      f16 bh8[8], bl8[8];
      splitf(b0.x, bh8[0], bl8[0]); splitf(b0.y, bh8[1], bl8[1]);
      splitf(b0.z, bh8[2], bl8[2]); splitf(b0.w, bh8[3], bl8[3]);
      splitf(b1.x, bh8[4], bl8[4]); splitf(b1.y, bh8[5], bl8[5]);
      splitf(b1.z, bh8[6], bl8[6]); splitf(b1.w, bh8[7], bl8[7]);
#pragma unroll
      for (int j = 0; j < 8; j++) { Bh[bn + j][bk2] = bh8[j]; Bl[bn + j][bk2] = bl8[j]; }
    }
    __syncthreads();
    f16x8 a_h[2], a_l[2];
#pragma unroll
    for (int mt = 0; mt < 2; mt++) {
      a_h[mt] = *(const f16x8*)&Ah[w * 32 + mt * 16 + lm][lk];
      a_l[mt] = *(const f16x8*)&Al[w * 32 + mt * 16 + lm][lk];
    }
#pragma unroll
    for (int nt = 0; nt < 4; nt++) {
      f16x8 b_h = *(const f16x8*)&Bh[nt * 16 + lm][lk];
      f16x8 b_l = *(const f16x8*)&Bl[nt * 16 + lm][lk];
#pragma unroll
      for (int mt = 0; mt < 2; mt++) {
        f32x4 c = acc[mt][nt];
        c = MFMA(a_h[mt], b_h, c);
        c = MFMA(a_h[mt], b_l, c);
        c = MFMA(a_l[mt], b_h, c);
        acc[mt][nt] = c;
      }
    }
    __syncthreads();
  }
#pragma unroll
  for (int mt = 0; mt < 2; mt++)
#pragma unroll
    for (int nt = 0; nt < 4; nt++) {
      int col = col0 + nt * 16 + lm;
      float bv_ = bias[col];
#pragma unroll
      for (int r = 0; r < 4; r++) {
        int row = row0 + w * 32 + mt * 16 + lg * 4 + r;
        float val = acc[mt][nt][r] + bv_;
        f16 h16, l16; splitf(val, h16, l16);
        outh[(size_t)row * D + col] = h16;
        outl[(size_t)row * D + col] = l16;
      }
    }
}

// ---------------- MFMA flash attention (no 1/sqrt(d) scale, per reference) ----------------
// grid (8 row-tiles, 32 b*h), 256 thr (4 waves, 16 q-rows each)
__global__ __launch_bounds__(256) void k_attn_mfma(
    const f16* __restrict__ qh, const f16* __restrict__ ql,
    const f16* __restrict__ kh, const f16* __restrict__ kl,
    const f16* __restrict__ vh, const f16* __restrict__ vl,
    float* __restrict__ o) {
  const int rt = blockIdx.x, bh = blockIdx.y;
  const int b = bh >> 3, h = bh & 7;
  const int row0 = rt * 64;
  __shared__ f16 Qh[64][40], Ql[64][40], Kh[64][40], Kl[64][40];
  __shared__ f16 Vth[32][72], Vtl[32][72];
  __shared__ f16 Ph[4][16][72], Pl[4][16][72];
  const int tid = threadIdx.x;
  const int lane = tid & 63, w = tid >> 6;
  const int lm = lane & 15, lg = lane >> 4, lk = lg * 8;
  const int sr = tid >> 2, sc = (tid & 3) * 8;
  {
    size_t gq = (size_t)(b * SS + row0 + sr) * D + h * HD + sc;
    *(f16x8*)&Qh[sr][sc] = *(const f16x8*)(qh + gq);
    *(f16x8*)&Ql[sr][sc] = *(const f16x8*)(ql + gq);
  }
  f32x4 accO[2] = {};
  float mrow[4], lsum[4];
#pragma unroll
  for (int r = 0; r < 4; r++) { mrow[r] = -1e30f; lsum[r] = 0.f; }
  for (int ct = 0; ct <= rt; ct++) {
    __syncthreads();
    {
      size_t gk = (size_t)(b * SS + ct * 64 + sr) * D + h * HD + sc;
      *(f16x8*)&Kh[sr][sc] = *(const f16x8*)(kh + gk);
      *(f16x8*)&Kl[sr][sc] = *(const f16x8*)(kl + gk);
      f16x8 hv = *(const f16x8*)(vh + gk);
      f16x8 lv = *(const f16x8*)(vl + gk);
#pragma unroll
      for (int j = 0; j < 8; j++) { Vth[sc + j][sr] = hv[j]; Vtl[sc + j][sr] = lv[j]; }
    }
    __syncthreads();
    f16x8 qfh = *(const f16x8*)&Qh[w * 16 + lm][lk];
    f16x8 qfl = *(const f16x8*)&Ql[w * 16 + lm][lk];
    f32x4 s[4];
#pragma unroll
    for (int nt = 0; nt < 4; nt++) {
      f16x8 kfh = *(const f16x8*)&Kh[nt * 16 + lm][lk];
      f16x8 kfl = *(const f16x8*)&Kl[nt * 16 + lm][lk];
      f32x4 c = {};
      c = MFMA(qfh, kfh, c);
      c = MFMA(qfh, kfl, c);
      c = MFMA(qfl, kfh, c);
      s[nt] = c;
    }
    if (ct == rt) {
#pragma unroll
      for (int nt = 0; nt < 4; nt++)
#pragma unroll
        for (int r = 0; r < 4; r++)
          if (nt * 16 + lm > w * 16 + lg * 4 + r) s[nt][r] = -1e30f;
    }
    float scal[4];
#pragma unroll
    for (int r = 0; r < 4; r++) {
      float mt2 = fmaxf(fmaxf(s[0][r], s[1][r]), fmaxf(s[2][r], s[3][r]));
      mt2 = fmaxf(mt2, __shfl_xor(mt2, 1));
      mt2 = fmaxf(mt2, __shfl_xor(mt2, 2));
      mt2 = fmaxf(mt2, __shfl_xor(mt2, 4));
      mt2 = fmaxf(mt2, __shfl_xor(mt2, 8));
      float mn = fmaxf(mrow[r], mt2);
      scal[r] = expf(mrow[r] - mn);
      mrow[r] = mn;
    }
    float rs[4] = {0.f, 0.f, 0.f, 0.f};
#pragma unroll
    for (int nt = 0; nt < 4; nt++)
#pragma unroll
      for (int r = 0; r < 4; r++) {
        float pv = expf(s[nt][r] - mrow[r]);
        rs[r] += pv;
        f16 ph16, pl16; splitf(pv, ph16, pl16);
        Ph[w][lg * 4 + r][nt * 16 + lm] = ph16;
        Pl[w][lg * 4 + r][nt * 16 + lm] = pl16;
      }
#pragma unroll
    for (int r = 0; r < 4; r++) {
      rs[r] += __shfl_xor(rs[r], 1);
      rs[r] += __shfl_xor(rs[r], 2);
      rs[r] += __shfl_xor(rs[r], 4);
      rs[r] += __shfl_xor(rs[r], 8);
      lsum[r] = lsum[r] * scal[r] + rs[r];
      accO[0][r] *= scal[r];
      accO[1][r] *= scal[r];
    }
#pragma unroll
    for (int ct2 = 0; ct2 < 2; ct2++)
#pragma unroll
      for (int ks = 0; ks < 2; ks++) {
        f16x8 pa_h = *(const f16x8*)&Ph[w][lm][ks * 32 + lk];
        f16x8 pa_l = *(const f16x8*)&Pl[w][lm][ks * 32 + lk];
        f16x8 vb_h = *(const f16x8*)&Vth[ct2 * 16 + lm][ks * 32 + lk];
        f16x8 vb_l = *(const f16x8*)&Vtl[ct2 * 16 + lm][ks * 32 + lk];
        accO[ct2] = MFMA(pa_h, vb_h, accO[ct2]);
        accO[ct2] = MFMA(pa_h, vb_l, accO[ct2]);
        accO[ct2] = MFMA(pa_l, vb_h, accO[ct2]);
      }
  }
#pragma unroll
  for (int ct2 = 0; ct2 < 2; ct2++)
#pragma unroll
    for (int r = 0; r < 4; r++) {
      int grow = row0 + w * 16 + lg * 4 + r;
      o[(size_t)(b * SS + grow) * D + h * HD + ct2 * 16 + lm] = accO[ct2][r] / lsum[r];
    }
}

// ---------------- residual + LN1 + parallel gate + top-2 ----------------
__global__ __launch_bounds__(256) void k_ln1gate(
    const float* __restrict__ o, const float* __restrict__ x,
    const float* __restrict__ s1, const float* __restrict__ b1,
    const float* __restrict__ gW, const float* __restrict__ gb,
    float* __restrict__ norm, f16* __restrict__ nhb, f16* __restrict__ nlb,
    int* __restrict__ eidx) {
  const int n = blockIdx.x, t = threadIdx.x;
  __shared__ float red[256];
  __shared__ float gl[NE];
  float val = o[(size_t)n * D + t] + x[(size_t)n * D + t];
  red[t] = val; __syncthreads();
  for (int s = 128; s > 0; s >>= 1) { if (t < s) red[t] += red[t + s]; __syncthreads(); }
  float m = red[0] * (1.f / D); __syncthreads();
  float df = val - m;
  red[t] = df * df; __syncthreads();
  for (int s = 128; s > 0; s >>= 1) { if (t < s) red[t] += red[t + s]; __syncthreads(); }
  float rstd = rsqrtf(red[0] * (1.f / D) + EPS); __syncthreads();
  float nv_ = df * rstd * s1[t] + b1[t];
  norm[(size_t)n * D + t] = nv_;
  f16 h16, l16; splitf(nv_, h16, l16);
  nhb[(size_t)n * D + t] = h16;
  nlb[(size_t)n * D + t] = l16;
  red[t] = nv_; __syncthreads();
  if (t < 192) {
    int e = t >> 4, di = t & 15;
    float acc = 0.f;
#pragma unroll
    for (int j = 0; j < 16; j++) acc += red[di + 16 * j] * gW[(di + 16 * j) * NE + e];
    acc += __shfl_xor(acc, 1);
    acc += __shfl_xor(acc, 2);
    acc += __shfl_xor(acc, 4);
    acc += __shfl_xor(acc, 8);
    if (di == 0) gl[e] = acc + gb[e];
  }
  __syncthreads();
  if (t == 0) {
    int i1 = 0; float v1 = gl[0];
    for (int e = 1; e < NE; e++) if (gl[e] > v1) { v1 = gl[e]; i1 = e; }
    int i2 = -1; float v2 = -3.4e38f;
    for (int e = 0; e < NE; e++) if (e != i1 && gl[e] > v2) { v2 = gl[e]; i2 = e; }
    eidx[n * 2 + 0] = i1;
    eidx[n * 2 + 1] = i2;
  }
}

// ---------------- routing: counts -> padded 128-row tiles -> scatter ----------------
__global__ __launch_bounds__(256) void k_route(const int* __restrict__ eidx,
                                               int* __restrict__ rlist, int* __restrict__ tokpos,
                                               int* __restrict__ te, int* __restrict__ tbase,
                                               int* __restrict__ tnv) {
  __shared__ int cnt[NE], cur[NE], poff[NE];
  const int t = threadIdx.x;
  if (t < NE) { cnt[t] = 0; cur[t] = 0; }
  __syncthreads();
  for (int n = t; n < NT; n += 256) {
    atomicAdd(&cnt[eidx[n * 2 + 0]], 1);
    atomicAdd(&cnt[eidx[n * 2 + 1]], 1);
  }
  __syncthreads();
  if (t == 0) {
    int off = 0, ti = 0;
    for (int e = 0; e < NE; e++) {
      poff[e] = off;
      int ntl = (cnt[e] + 127) >> 7;
      for (int tt = 0; tt < ntl; tt++) {
        te[ti] = e; tbase[ti] = off + tt * 128;
        int rem = cnt[e] - tt * 128; tnv[ti] = rem < 128 ? rem : 128;
        ti++;
      }
      off += ntl * 128;
    }
    for (; ti < MAXT; ti++) te[ti] = -1;
  }
  __syncthreads();
  for (int n = t; n < NT; n += 256) {
#pragma unroll
    for (int s2 = 0; s2 < 2; s2++) {
      int e = eidx[n * 2 + s2];
      int pos = atomicAdd(&cur[e], 1);
      int row = poff[e] + pos;
      rlist[row] = n;
      tokpos[n * 2 + s2] = row;
    }
  }
}

// ---------------- MoE up-projection, 128x64 tiles: h = silu(n@W1+b1)*(n@Wg+bg) ----------------
// grid (MAXT, 8), 256 thr
__global__ __launch_bounds__(256) void k_ff1_mfma(
    const f16* __restrict__ nhb, const f16* __restrict__ nlb,
    const int* __restrict__ rlist,
    const int* __restrict__ te, const int* __restrict__ tbase, const int* __restrict__ tnv,
    const float* __restrict__ W1, const float* __restrict__ b1f,
    const float* __restrict__ Wg, const float* __restrict__ bgf,
    f16* __restrict__ hhb, f16* __restrict__ hlb) {
  const int mt0 = blockIdx.x;
  const int e = te[mt0];
  if (e < 0) return;
  const int base = tbase[mt0], nv = tnv[mt0];
  const int col0 = blockIdx.y * 64;
  const float* W1e = W1 + (size_t)e * D * FF;
  const float* Wge = Wg + (size_t)e * D * FF;
  __shared__ f16 Ah[128][40], Al[128][40];
  __shared__ f16 B1h[64][40], B1l[64][40], B2h[64][40], B2l[64][40];
  __shared__ int rows[128];
  const int tid = threadIdx.x;
  if (tid < 128) rows[tid] = (tid < nv) ? rlist[base + tid] : 0;
  __syncthreads();
  const int asr = tid >> 1, asc = (tid & 1) * 16;
  const int bk2 = tid >> 3, bn = (tid & 7) * 8;
  const int lane = tid & 63, w = tid >> 6;
  const int lm = lane & 15, lg = lane >> 4, lk = lg * 8;
  f32x4 acc1[2][4] = {}, acc2[2][4] = {};
  const int arow = rows[asr];
  for (int k0 = 0; k0 < D; k0 += 32) {
    {
      size_t ga = (size_t)arow * D + k0 + asc;
      *(f16x8*)&Ah[asr][asc]     = *(const f16x8*)(nhb + ga);
      *(f16x8*)&Ah[asr][asc + 8] = *(const f16x8*)(nhb + ga + 8);
      *(f16x8*)&Al[asr][asc]     = *(const f16x8*)(nlb + ga);
      *(f16x8*)&Al[asr][asc + 8] = *(const f16x8*)(nlb + ga + 8);
      const float* b1p = W1e + (size_t)(k0 + bk2) * FF + col0 + bn;
      const float* b2p = Wge + (size_t)(k0 + bk2) * FF + col0 + bn;
      float4 u0 = *(const float4*)b1p;
      float4 u1 = *(const float4*)(b1p + 4);
      float4 g0 = *(const float4*)b2p;
      float4 g1 = *(const float4*)(b2p + 4);
      f16 bh8[8], bl8[8], ch8[8], cl8[8];
      splitf(u0.x, bh8[0], bl8[0]); splitf(u0.y, bh8[1], bl8[1]);
      splitf(u0.z, bh8[2], bl8[2]); splitf(u0.w, bh8[3], bl8[3]);
      splitf(u1.x, bh8[4], bl8[4]); splitf(u1.y, bh8[5], bl8[5]);
      splitf(u1.z, bh8[6], bl8[6]); splitf(u1.w, bh8[7], bl8[7]);
      splitf(g0.x, ch8[0], cl8[0]); splitf(g0.y, ch8[1], cl8[1]);
      splitf(g0.z, ch8[2], cl8[2]); splitf(g0.w, ch8[3], cl8[3]);
      splitf(g1.x, ch8[4], cl8[4]); splitf(g1.y, ch8[5], cl8[5]);
      splitf(g1.z, ch8[6], cl8[6]); splitf(g1.w, ch8[7], cl8[7]);
#pragma unroll
      for (int j = 0; j < 8; j++) {
        B1h[bn + j][bk2] = bh8[j]; B1l[bn + j][bk2] = bl8[j];
        B2h[bn + j][bk2] = ch8[j]; B2l[bn + j][bk2] = cl8[j];
      }
    }
    __syncthreads();
    f16x8 a_h[2], a_l[2];
#pragma unroll
    for (int mt = 0; mt < 2; mt++) {
      a_h[mt] = *(const f16x8*)&Ah[w * 32 + mt * 16 + lm][lk];
      a_l[mt] = *(const f16x8*)&Al[w * 32 + mt * 16 + lm][lk];
    }
#pragma unroll
    for (int nt = 0; nt < 4; nt++) {
      f16x8 b_h = *(const f16x8*)&B1h[nt * 16 + lm][lk];
      f16x8 b_l = *(const f16x8*)&B1l[nt * 16 + lm][lk];
      f16x8 c_h = *(const f16x8*)&B2h[nt * 16 + lm][lk];
      f16x8 c_l = *(const f16x8*)&B2l[nt * 16 + lm][lk];
#pragma unroll
      for (int mt = 0; mt < 2; mt++) {
        f32x4 c1 = acc1[mt][nt];
        c1 = MFMA(a_h[mt], b_h, c1);
        c1 = MFMA(a_h[mt], b_l, c1);
        c1 = MFMA(a_l[mt], b_h, c1);
        acc1[mt][nt] = c1;
        f32x4 c2 = acc2[mt][nt];
        c2 = MFMA(a_h[mt], c_h, c2);
        c2 = MFMA(a_h[mt], c_l, c2);
        c2 = MFMA(a_l[mt], c_h, c2);
        acc2[mt][nt] = c2;
      }
    }
    __syncthreads();
  }
#pragma unroll
  for (int mt = 0; mt < 2; mt++)
#pragma unroll
    for (int nt = 0; nt < 4; nt++) {
      int col = col0 + nt * 16 + lm;
      float bb1 = b1f[e * FF + col], bb2 = bgf[e * FF + col];
#pragma unroll
      for (int r = 0; r < 4; r++) {
        int rit = w * 32 + mt * 16 + lg * 4 + r;
        if (rit < nv) {
          float z1 = acc1[mt][nt][r] + bb1;
          float zg = acc2[mt][nt][r] + bb2;
          float sl = z1 / (1.f + expf(-z1));
          float hv = sl * zg;
          f16 h16, l16; splitf(hv, h16, l16);
          hhb[(size_t)(base + rit) * FF + col] = h16;
          hlb[(size_t)(base + rit) * FF + col] = l16;
        }
      }
    }
}

// ---------------- MoE down-projection, 128x64 tiles: y = h@W2 + b2 ----------------
// grid (MAXT, 4), 256 thr
__global__ __launch_bounds__(256) void k_ff2_mfma(
    const f16* __restrict__ hhb, const f16* __restrict__ hlb,
    const int* __restrict__ te, const int* __restrict__ tbase, const int* __restrict__ tnv,
    const float* __restrict__ W2, const float* __restrict__ b2f,
    float* __restrict__ ybuf) {
  const int mt0 = blockIdx.x;
  const int e = te[mt0];
  if (e < 0) return;
  const int base = tbase[mt0], nv = tnv[mt0];
  const int col0 = blockIdx.y * 64;
  const float* W2e = W2 + (size_t)e * FF * D;
  __shared__ f16 Ah[128][40], Al[128][40], Bh[64][40], Bl[64][40];
  const int tid = threadIdx.x;
  const int asr = tid >> 1, asc = (tid & 1) * 16;
  const int bk2 = tid >> 3, bn = (tid & 7) * 8;
  const int lane = tid & 63, w = tid >> 6;
  const int lm = lane & 15, lg = lane >> 4, lk = lg * 8;
  f32x4 acc[2][4] = {};
  for (int k0 = 0; k0 < FF; k0 += 32) {
    {
      size_t ga = (size_t)(base + asr) * FF + k0 + asc;
      *(f16x8*)&Ah[asr][asc]     = *(const f16x8*)(hhb + ga);
      *(f16x8*)&Ah[asr][asc + 8] = *(const f16x8*)(hhb + ga + 8);
      *(f16x8*)&Al[asr][asc]     = *(const f16x8*)(hlb + ga);
      *(f16x8*)&Al[asr][asc + 8] = *(const f16x8*)(hlb + ga + 8);
      const float* bp = W2e + (size_t)(k0 + bk2) * D + col0 + bn;
      float4 b0 = *(const float4*)bp;
      float4 b1 = *(const float4*)(bp + 4);
      f16 bh8[8], bl8[8];
      splitf(b0.x, bh8[0], bl8[0]); splitf(b0.y, bh8[1], bl8[1]);
      splitf(b0.z, bh8[2], bl8[2]); splitf(b0.w, bh8[3], bl8[3]);
      splitf(b1.x, bh8[4], bl8[4]); splitf(b1.y, bh8[5], bl8[5]);
      splitf(b1.z, bh8[6], bl8[6]); splitf(b1.w, bh8[7], bl8[7]);
#pragma unroll
      for (int j = 0; j < 8; j++) { Bh[bn + j][bk2] = bh8[j]; Bl[bn + j][bk2] = bl8[j]; }
    }
    __syncthreads();
    f16x8 a_h[2], a_l[2];
#pragma unroll
    for (int mt = 0; mt < 2; mt++) {
      a_h[mt] = *(const f16x8*)&Ah[w * 32 + mt * 16 + lm][lk];
      a_l[mt] = *(const f16x8*)&Al[w * 32 + mt * 16 + lm][lk];
    }
#pragma unroll
    for (int nt = 0; nt < 4; nt++) {
      f16x8 b_h = *(const f16x8*)&Bh[nt * 16 + lm][lk];
      f16x8 b_l = *(const f16x8*)&Bl[nt * 16 + lm][lk];
#pragma unroll
      for (int mt = 0; mt < 2; mt++) {
        f32x4 c = acc[mt][nt];
        c = MFMA(a_h[mt], b_h, c);
        c = MFMA(a_h[mt], b_l, c);
        c = MFMA(a_l[mt], b_h, c);
        acc[mt][nt] = c;
      }
    }
    __syncthreads();
  }
#pragma unroll
  for (int mt = 0; mt < 2; mt++)
#pragma unroll
    for (int nt = 0; nt < 4; nt++) {
      int col = col0 + nt * 16 + lm;
      float bb = b2f[e * D + col];
#pragma unroll
      for (int r = 0; r < 4; r++) {
        int rit = w * 32 + mt * 16 + lg * 4 + r;
        if (rit < nv) ybuf[(size_t)(base + rit) * D + col] = acc[mt][nt][r] + bb;
      }
    }
}

// ---------------- moe-sum + residual + LN2 + split ----------------
__global__ __launch_bounds__(256) void k_ln2(
    const float* __restrict__ ybuf, const int* __restrict__ tokpos,
    const float* __restrict__ norm, const float* __restrict__ s2, const float* __restrict__ b2,
    float* __restrict__ out, f16* __restrict__ xh, f16* __restrict__ xl) {
  const int n = blockIdx.x, t = threadIdx.x;
  __shared__ float red[256];
  int p0 = tokpos[n * 2 + 0], p1 = tokpos[n * 2 + 1];
  float val = ybuf[(size_t)p0 * D + t] + ybuf[(size_t)p1 * D + t] + norm[(size_t)n * D + t];
  red[t] = val; __syncthreads();
  for (int s = 128; s > 0; s >>= 1) { if (t < s) red[t] += red[t + s]; __syncthreads(); }
  float m = red[0] * (1.f / D); __syncthreads();
  float df = val - m;
  red[t] = df * df; __syncthreads();
  for (int s = 128; s > 0; s >>= 1) { if (t < s) red[t] += red[t + s]; __syncthreads(); }
  float rstd = rsqrtf(red[0] * (1.f / D) + EPS);
  float ov = df * rstd * s2[t] + b2[t];
  out[(size_t)n * D + t] = ov;
  f16 h16, l16; splitf(ov, h16, l16);
  xh[(size_t)n * D + t] = h16;
  xl[(size_t)n * D + t] = l16;
}

extern "C" void kernel_launch(void* const* d_in, const int* in_sizes, int n_in,
                              void* d_out, int out_size, void* d_ws, size_t ws_size,
                              hipStream_t stream) {
  (void)in_sizes; (void)n_in; (void)out_size; (void)ws_size;
  const int*   tok = (const int*)d_in[0];
  const float* emb = (const float*)d_in[1];
  const float* Wq  = (const float*)d_in[2];
  const float* bq  = (const float*)d_in[3];
  const float* Wk  = (const float*)d_in[4];
  const float* bk  = (const float*)d_in[5];
  const float* Wv  = (const float*)d_in[6];
  const float* bv  = (const float*)d_in[7];
  const float* l1s = (const float*)d_in[8];
  const float* l1b = (const float*)d_in[9];
  const float* l2s = (const float*)d_in[10];
  const float* l2b = (const float*)d_in[11];
  const float* gW  = (const float*)d_in[12];
  const float* gb  = (const float*)d_in[13];
  const float* f1W = (const float*)d_in[14];
  const float* f1b = (const float*)d_in[15];
  const float* fgW = (const float*)d_in[16];
  const float* fgb = (const float*)d_in[17];
  const float* f2W = (const float*)d_in[18];
  const float* f2b = (const float*)d_in[19];
  float* out = (float*)d_out;

  char* p = (char*)d_ws;
  auto alloc = [&](size_t bytes) { char* r = p; p += (bytes + 255) & ~(size_t)255; return r; };
  float* xb = (float*)alloc((size_t)NT * D * 4);
  f16* xh = (f16*)alloc((size_t)NT * D * 2);
  f16* xl = (f16*)alloc((size_t)NT * D * 2);
  f16* qhb = (f16*)alloc((size_t)NT * D * 2);
  f16* qlb = (f16*)alloc((size_t)NT * D * 2);
  f16* khb = (f16*)alloc((size_t)NT * D * 2);
  f16* klb = (f16*)alloc((size_t)NT * D * 2);
  f16* vhb = (f16*)alloc((size_t)NT * D * 2);
  f16* vlb = (f16*)alloc((size_t)NT * D * 2);
  float* ob = (float*)alloc((size_t)NT * D * 4);
  float* nb = (float*)alloc((size_t)NT * D * 4);
  f16* nhb = (f16*)alloc((size_t)NT * D * 2);
  f16* nlb = (f16*)alloc((size_t)NT * D * 2);
  f16* hhb = (f16*)alloc((size_t)PADROWS * FF * 2);
  f16* hlb = (f16*)alloc((size_t)PADROWS * FF * 2);
  float* yb = (float*)alloc((size_t)PADROWS * D * 4);
  int* eidx   = (int*)alloc((size_t)NT * 2 * 4);
  int* rlist  = (int*)alloc((size_t)PADROWS * 4);
  int* tokpos = (int*)alloc((size_t)NT * 2 * 4);
  int* te     = (int*)alloc(MAXT * 4);
  int* tbase  = (int*)alloc(MAXT * 4);
  int* tnv    = (int*)alloc(MAXT * 4);

  k_embed<<<NT, 256, 0, stream>>>(tok, emb, xb, xh, xl);

  for (int l = 0; l < LNUM; l++) {
    k_qkv_mfma<<<dim3(16, 4, 3), 256, 0, stream>>>(
        xh, xl,
        Wq + (size_t)l * D * D, bq + (size_t)l * D,
        Wk + (size_t)l * D * D, bk + (size_t)l * D,
        Wv + (size_t)l * D * D, bv + (size_t)l * D,
        qhb, qlb, khb, klb, vhb, vlb);
    k_attn_mfma<<<dim3(8, 32), 256, 0, stream>>>(qhb, qlb, khb, klb, vhb, vlb, ob);
    k_ln1gate<<<NT, 256, 0, stream>>>(ob, xb, l1s + (size_t)l * D, l1b + (size_t)l * D,
                                      gW + (size_t)l * D * NE, gb + (size_t)l * NE,
                                      nb, nhb, nlb, eidx);
    k_route<<<1, 256, 0, stream>>>(eidx, rlist, tokpos, te, tbase, tnv);
    k_ff1_mfma<<<dim3(MAXT, 8), 256, 0, stream>>>(
        nhb, nlb, rlist, te, tbase, tnv,
        f1W + (size_t)l * NE * D * FF, f1b + (size_t)l * NE * FF,
        fgW + (size_t)l * NE * D * FF, fgb + (size_t)l * NE * FF, hhb, hlb);
    k_ff2_mfma<<<dim3(MAXT, 4), 256, 0, stream>>>(
        hhb, hlb, te, tbase, tnv,
        f2W + (size_t)l * NE * FF * D, f2b + (size_t)l * NE * D, yb);
    k_ln2<<<NT, 256, 0, stream>>>(yb, tokpos, nb, l2s + (size_t)l * D, l2b + (size_t)l * D,
                                  (l == LNUM - 1) ? out : xb, xh, xl);
  }
}

// Round 5
// 1974.024 us; speedup vs baseline: 1.4975x; 1.0251x over previous
//
#include <hip/hip_runtime.h>
#include <math.h>

#define LNUM 16
#define D 256
#define FF 512
#define NH 8
#define NE 12
#define HD 32
#define BB 4
#define SS 512
#define NT 2048      // B*S
#define EPS 1e-5f
#define MAXT 48
#define PADROWS 5632

typedef _Float16 f16;
typedef __attribute__((ext_vector_type(8))) _Float16 f16x8;
typedef __attribute__((ext_vector_type(4))) _Float16 f16x4;
typedef __attribute__((ext_vector_type(4))) float f32x4;
#define MFMA(A, B, C) __builtin_amdgcn_mfma_f32_16x16x32_f16((A), (B), (C), 0, 0, 0)

__device__ inline void splitf(float x, f16& h, f16& l) {
  f16 hh = (f16)x;
  h = hh;
  l = (f16)(x - (float)hh);
}

// ---------------- weight prep: [K][N] fp32 -> hi/lo [N][K] f16 (per-mat z) ----------------
__global__ __launch_bounds__(256) void k_wprep(const float* __restrict__ src,
                                               f16* __restrict__ dh, f16* __restrict__ dl,
                                               int K, int N) {
  const size_t msz = (size_t)K * N * blockIdx.z;
  src += msz; dh += msz; dl += msz;
  const int n0 = blockIdx.x * 32, k0 = blockIdx.y * 32;
  __shared__ f16 th[32][36], tl[32][36];
  const int t = threadIdx.x;
  {
    const int r = t >> 3, c4 = (t & 7) * 4;
    float4 v = *(const float4*)(src + (size_t)(k0 + r) * N + n0 + c4);
    f16 h0, l0, h1, l1, h2, l2, h3, l3;
    splitf(v.x, h0, l0); splitf(v.y, h1, l1);
    splitf(v.z, h2, l2); splitf(v.w, h3, l3);
    th[c4 + 0][r] = h0; tl[c4 + 0][r] = l0;
    th[c4 + 1][r] = h1; tl[c4 + 1][r] = l1;
    th[c4 + 2][r] = h2; tl[c4 + 2][r] = l2;
    th[c4 + 3][r] = h3; tl[c4 + 3][r] = l3;
  }
  __syncthreads();
  const int rn = t >> 3, ck = (t & 7) * 4;
  f16x4 hv, lv;
#pragma unroll
  for (int j = 0; j < 4; j++) { hv[j] = th[rn][ck + j]; lv[j] = tl[rn][ck + j]; }
  *(f16x4*)(dh + (size_t)(n0 + rn) * K + k0 + ck) = hv;
  *(f16x4*)(dl + (size_t)(n0 + rn) * K + k0 + ck) = lv;
}

// ---------------- embedding gather + split ----------------
__global__ __launch_bounds__(256) void k_embed(const int* __restrict__ tok,
                                               const float* __restrict__ emb,
                                               float* __restrict__ x,
                                               f16* __restrict__ xh, f16* __restrict__ xl) {
  int n = blockIdx.x, t = threadIdx.x;
  float val = emb[(size_t)tok[n] * D + t];
  x[(size_t)n * D + t] = val;
  f16 h, l; splitf(val, h, l);
  xh[(size_t)n * D + t] = h;
  xl[(size_t)n * D + t] = l;
}

// ---------------- QKV projection, 128x64 tiles, pre-split weights ----------------
// grid (16 row-tiles, 4 col-tiles, 3 mats), 256 thr
__global__ __launch_bounds__(256) void k_qkv_mfma(
    const f16* __restrict__ xh, const f16* __restrict__ xl,
    const f16* __restrict__ wqh, const f16* __restrict__ wql, const float* __restrict__ bq,
    const f16* __restrict__ wkh, const f16* __restrict__ wkl, const float* __restrict__ bk,
    const f16* __restrict__ wvh, const f16* __restrict__ wvl, const float* __restrict__ bv,
    f16* __restrict__ qhb, f16* __restrict__ qlb,
    f16* __restrict__ khb, f16* __restrict__ klb,
    f16* __restrict__ vhb, f16* __restrict__ vlb) {
  const f16* Wh; const f16* Wl; const float* bias; f16* outh; f16* outl;
  if (blockIdx.z == 0)      { Wh = wqh; Wl = wql; bias = bq; outh = qhb; outl = qlb; }
  else if (blockIdx.z == 1) { Wh = wkh; Wl = wkl; bias = bk; outh = khb; outl = klb; }
  else                      { Wh = wvh; Wl = wvl; bias = bv; outh = vhb; outl = vlb; }
  const int row0 = blockIdx.x * 128, col0 = blockIdx.y * 64;
  __shared__ f16 Ah[128][44], Al[128][44], Bh[64][44], Bl[64][44];
  const int tid = threadIdx.x;
  const int asr = tid >> 1, asc = (tid & 1) * 16;
  const int bn2 = tid >> 2, bkc = (tid & 3) * 8;
  const int lane = tid & 63, w = tid >> 6;
  const int lm = lane & 15, lg = lane >> 4, lk = lg * 8;
  f32x4 acc[2][4] = {};
  for (int k0 = 0; k0 < D; k0 += 32) {
    {
      size_t ga = (size_t)(row0 + asr) * D + k0 + asc;
      *(f16x8*)&Ah[asr][asc]     = *(const f16x8*)(xh + ga);
      *(f16x8*)&Ah[asr][asc + 8] = *(const f16x8*)(xh + ga + 8);
      *(f16x8*)&Al[asr][asc]     = *(const f16x8*)(xl + ga);
      *(f16x8*)&Al[asr][asc + 8] = *(const f16x8*)(xl + ga + 8);
      size_t gb = (size_t)(col0 + bn2) * D + k0 + bkc;
      *(f16x8*)&Bh[bn2][bkc] = *(const f16x8*)(Wh + gb);
      *(f16x8*)&Bl[bn2][bkc] = *(const f16x8*)(Wl + gb);
    }
    __syncthreads();
    f16x8 a_h[2], a_l[2];
#pragma unroll
    for (int mt = 0; mt < 2; mt++) {
      a_h[mt] = *(const f16x8*)&Ah[w * 32 + mt * 16 + lm][lk];
      a_l[mt] = *(const f16x8*)&Al[w * 32 + mt * 16 + lm][lk];
    }
#pragma unroll
    for (int nt = 0; nt < 4; nt++) {
      f16x8 b_h = *(const f16x8*)&Bh[nt * 16 + lm][lk];
      f16x8 b_l = *(const f16x8*)&Bl[nt * 16 + lm][lk];
#pragma unroll
      for (int mt = 0; mt < 2; mt++) {
        f32x4 c = acc[mt][nt];
        c = MFMA(a_h[mt], b_h, c);
        c = MFMA(a_h[mt], b_l, c);
        c = MFMA(a_l[mt], b_h, c);
        acc[mt][nt] = c;
      }
    }
    __syncthreads();
  }
#pragma unroll
  for (int mt = 0; mt < 2; mt++)
#pragma unroll
    for (int nt = 0; nt < 4; nt++) {
      int col = col0 + nt * 16 + lm;
      float bv_ = bias[col];
#pragma unroll
      for (int r = 0; r < 4; r++) {
        int row = row0 + w * 32 + mt * 16 + lg * 4 + r;
        float val = acc[mt][nt][r] + bv_;
        f16 h16, l16; splitf(val, h16, l16);
        outh[(size_t)row * D + col] = h16;
        outl[(size_t)row * D + col] = l16;
      }
    }
}

// ---------------- MFMA flash attention (no 1/sqrt(d) scale, per reference) ----------------
// grid (8 row-tiles, 32 b*h), 256 thr (4 waves, 16 q-rows each)
__global__ __launch_bounds__(256) void k_attn_mfma(
    const f16* __restrict__ qh, const f16* __restrict__ ql,
    const f16* __restrict__ kh, const f16* __restrict__ kl,
    const f16* __restrict__ vh, const f16* __restrict__ vl,
    float* __restrict__ o) {
  const int rt = blockIdx.x, bh = blockIdx.y;
  const int b = bh >> 3, h = bh & 7;
  const int row0 = rt * 64;
  __shared__ f16 Qh[64][40], Ql[64][40], Kh[64][40], Kl[64][40];
  __shared__ f16 Vth[32][72], Vtl[32][72];
  __shared__ f16 Ph[4][16][72], Pl[4][16][72];
  const int tid = threadIdx.x;
  const int lane = tid & 63, w = tid >> 6;
  const int lm = lane & 15, lg = lane >> 4, lk = lg * 8;
  const int sr = tid >> 2, sc = (tid & 3) * 8;
  {
    size_t gq = (size_t)(b * SS + row0 + sr) * D + h * HD + sc;
    *(f16x8*)&Qh[sr][sc] = *(const f16x8*)(qh + gq);
    *(f16x8*)&Ql[sr][sc] = *(const f16x8*)(ql + gq);
  }
  f32x4 accO[2] = {};
  float mrow[4], lsum[4];
#pragma unroll
  for (int r = 0; r < 4; r++) { mrow[r] = -1e30f; lsum[r] = 0.f; }
  for (int ct = 0; ct <= rt; ct++) {
    __syncthreads();
    {
      size_t gk = (size_t)(b * SS + ct * 64 + sr) * D + h * HD + sc;
      *(f16x8*)&Kh[sr][sc] = *(const f16x8*)(kh + gk);
      *(f16x8*)&Kl[sr][sc] = *(const f16x8*)(kl + gk);
      f16x8 hv = *(const f16x8*)(vh + gk);
      f16x8 lv = *(const f16x8*)(vl + gk);
#pragma unroll
      for (int j = 0; j < 8; j++) { Vth[sc + j][sr] = hv[j]; Vtl[sc + j][sr] = lv[j]; }
    }
    __syncthreads();
    f16x8 qfh = *(const f16x8*)&Qh[w * 16 + lm][lk];
    f16x8 qfl = *(const f16x8*)&Ql[w * 16 + lm][lk];
    f32x4 s[4];
#pragma unroll
    for (int nt = 0; nt < 4; nt++) {
      f16x8 kfh = *(const f16x8*)&Kh[nt * 16 + lm][lk];
      f16x8 kfl = *(const f16x8*)&Kl[nt * 16 + lm][lk];
      f32x4 c = {};
      c = MFMA(qfh, kfh, c);
      c = MFMA(qfh, kfl, c);
      c = MFMA(qfl, kfh, c);
      s[nt] = c;
    }
    if (ct == rt) {
#pragma unroll
      for (int nt = 0; nt < 4; nt++)
#pragma unroll
        for (int r = 0; r < 4; r++)
          if (nt * 16 + lm > w * 16 + lg * 4 + r) s[nt][r] = -1e30f;
    }
    float scal[4];
#pragma unroll
    for (int r = 0; r < 4; r++) {
      float mt2 = fmaxf(fmaxf(s[0][r], s[1][r]), fmaxf(s[2][r], s[3][r]));
      mt2 = fmaxf(mt2, __shfl_xor(mt2, 1));
      mt2 = fmaxf(mt2, __shfl_xor(mt2, 2));
      mt2 = fmaxf(mt2, __shfl_xor(mt2, 4));
      mt2 = fmaxf(mt2, __shfl_xor(mt2, 8));
      float mn = fmaxf(mrow[r], mt2);
      scal[r] = expf(mrow[r] - mn);
      mrow[r] = mn;
    }
    float rs[4] = {0.f, 0.f, 0.f, 0.f};
#pragma unroll
    for (int nt = 0; nt < 4; nt++)
#pragma unroll
      for (int r = 0; r < 4; r++) {
        float pv = expf(s[nt][r] - mrow[r]);
        rs[r] += pv;
        f16 ph16, pl16; splitf(pv, ph16, pl16);
        Ph[w][lg * 4 + r][nt * 16 + lm] = ph16;
        Pl[w][lg * 4 + r][nt * 16 + lm] = pl16;
      }
#pragma unroll
    for (int r = 0; r < 4; r++) {
      rs[r] += __shfl_xor(rs[r], 1);
      rs[r] += __shfl_xor(rs[r], 2);
      rs[r] += __shfl_xor(rs[r], 4);
      rs[r] += __shfl_xor(rs[r], 8);
      lsum[r] = lsum[r] * scal[r] + rs[r];
      accO[0][r] *= scal[r];
      accO[1][r] *= scal[r];
    }
#pragma unroll
    for (int ct2 = 0; ct2 < 2; ct2++)
#pragma unroll
      for (int ks = 0; ks < 2; ks++) {
        f16x8 pa_h = *(const f16x8*)&Ph[w][lm][ks * 32 + lk];
        f16x8 pa_l = *(const f16x8*)&Pl[w][lm][ks * 32 + lk];
        f16x8 vb_h = *(const f16x8*)&Vth[ct2 * 16 + lm][ks * 32 + lk];
        f16x8 vb_l = *(const f16x8*)&Vtl[ct2 * 16 + lm][ks * 32 + lk];
        accO[ct2] = MFMA(pa_h, vb_h, accO[ct2]);
        accO[ct2] = MFMA(pa_h, vb_l, accO[ct2]);
        accO[ct2] = MFMA(pa_l, vb_h, accO[ct2]);
      }
  }
#pragma unroll
  for (int ct2 = 0; ct2 < 2; ct2++)
#pragma unroll
    for (int r = 0; r < 4; r++) {
      int grow = row0 + w * 16 + lg * 4 + r;
      o[(size_t)(b * SS + grow) * D + h * HD + ct2 * 16 + lm] = accO[ct2][r] / lsum[r];
    }
}

// ---------------- wave-per-token: residual + LN1 + gate + top-2 ----------------
// grid 512, 256 thr (4 waves = 4 tokens)
__global__ __launch_bounds__(256) void k_ln1gate(
    const float* __restrict__ o, const float* __restrict__ x,
    const float* __restrict__ s1, const float* __restrict__ b1,
    const float* __restrict__ gW, const float* __restrict__ gb,
    float* __restrict__ norm, f16* __restrict__ nhb, f16* __restrict__ nlb,
    int* __restrict__ eidx) {
  const int w = threadIdx.x >> 6, lane = threadIdx.x & 63;
  const int n = blockIdx.x * 4 + w;
  float val[4], s1v = 0.f, s2v = 0.f;
#pragma unroll
  for (int j = 0; j < 4; j++) {
    int d = lane + 64 * j;
    float v = o[(size_t)n * D + d] + x[(size_t)n * D + d];
    val[j] = v; s1v += v; s2v += v * v;
  }
#pragma unroll
  for (int m = 1; m < 64; m <<= 1) {
    s1v += __shfl_xor(s1v, m);
    s2v += __shfl_xor(s2v, m);
  }
  float mean = s1v * (1.f / D);
  float var = s2v * (1.f / D) - mean * mean;
  float rstd = rsqrtf(var + EPS);
  float ge[NE];
#pragma unroll
  for (int e = 0; e < NE; e++) ge[e] = 0.f;
#pragma unroll
  for (int j = 0; j < 4; j++) {
    int d = lane + 64 * j;
    float nv = (val[j] - mean) * rstd * s1[d] + b1[d];
    norm[(size_t)n * D + d] = nv;
    f16 h16, l16; splitf(nv, h16, l16);
    nhb[(size_t)n * D + d] = h16;
    nlb[(size_t)n * D + d] = l16;
    const float* gr = gW + (size_t)d * NE;
#pragma unroll
    for (int e = 0; e < NE; e++) ge[e] += nv * gr[e];
  }
#pragma unroll
  for (int m = 1; m < 64; m <<= 1)
#pragma unroll
    for (int e = 0; e < NE; e++) ge[e] += __shfl_xor(ge[e], m);
  if (lane == 0) {
#pragma unroll
    for (int e = 0; e < NE; e++) ge[e] += gb[e];
    int i1 = 0; float v1 = ge[0];
#pragma unroll
    for (int e = 1; e < NE; e++) if (ge[e] > v1) { v1 = ge[e]; i1 = e; }
    int i2 = -1; float v2 = -3.4e38f;
#pragma unroll
    for (int e = 0; e < NE; e++) if (e != i1 && ge[e] > v2) { v2 = ge[e]; i2 = e; }
    eidx[n * 2 + 0] = i1;
    eidx[n * 2 + 1] = i2;
  }
}

// ---------------- routing: counts -> padded 128-row tiles -> scatter ----------------
__global__ __launch_bounds__(256) void k_route(const int* __restrict__ eidx,
                                               int* __restrict__ rlist, int* __restrict__ tokpos,
                                               int* __restrict__ te, int* __restrict__ tbase,
                                               int* __restrict__ tnv) {
  __shared__ int cnt[NE], cur[NE], poff[NE];
  const int t = threadIdx.x;
  if (t < NE) { cnt[t] = 0; cur[t] = 0; }
  __syncthreads();
  for (int n = t; n < NT; n += 256) {
    atomicAdd(&cnt[eidx[n * 2 + 0]], 1);
    atomicAdd(&cnt[eidx[n * 2 + 1]], 1);
  }
  __syncthreads();
  if (t == 0) {
    int off = 0, ti = 0;
    for (int e = 0; e < NE; e++) {
      poff[e] = off;
      int ntl = (cnt[e] + 127) >> 7;
      for (int tt = 0; tt < ntl; tt++) {
        te[ti] = e; tbase[ti] = off + tt * 128;
        int rem = cnt[e] - tt * 128; tnv[ti] = rem < 128 ? rem : 128;
        ti++;
      }
      off += ntl * 128;
    }
    for (; ti < MAXT; ti++) te[ti] = -1;
  }
  __syncthreads();
  for (int n = t; n < NT; n += 256) {
#pragma unroll
    for (int s2 = 0; s2 < 2; s2++) {
      int e = eidx[n * 2 + s2];
      int pos = atomicAdd(&cur[e], 1);
      int row = poff[e] + pos;
      rlist[row] = n;
      tokpos[n * 2 + s2] = row;
    }
  }
}

// ---------------- MoE up-projection, 128x64 tiles, pre-split weights ----------------
// grid (MAXT, 8), 256 thr
__global__ __launch_bounds__(256) void k_ff1_mfma(
    const f16* __restrict__ nhb, const f16* __restrict__ nlb,
    const int* __restrict__ rlist,
    const int* __restrict__ te, const int* __restrict__ tbase, const int* __restrict__ tnv,
    const f16* __restrict__ w1th, const f16* __restrict__ w1tl, const float* __restrict__ b1f,
    const f16* __restrict__ wgth, const f16* __restrict__ wgtl, const float* __restrict__ bgf,
    f16* __restrict__ hhb, f16* __restrict__ hlb) {
  const int mt0 = blockIdx.x;
  const int e = te[mt0];
  if (e < 0) return;
  const int base = tbase[mt0], nv = tnv[mt0];
  const int col0 = blockIdx.y * 64;
  const f16* W1h = w1th + (size_t)e * D * FF;
  const f16* W1l = w1tl + (size_t)e * D * FF;
  const f16* Wgh = wgth + (size_t)e * D * FF;
  const f16* Wgl = wgtl + (size_t)e * D * FF;
  __shared__ f16 Ah[128][44], Al[128][44];
  __shared__ f16 B1h[64][44], B1l[64][44], B2h[64][44], B2l[64][44];
  __shared__ int rows[128];
  const int tid = threadIdx.x;
  if (tid < 128) rows[tid] = (tid < nv) ? rlist[base + tid] : 0;
  __syncthreads();
  const int asr = tid >> 1, asc = (tid & 1) * 16;
  const int bn2 = tid >> 2, bkc = (tid & 3) * 8;
  const int lane = tid & 63, w = tid >> 6;
  const int lm = lane & 15, lg = lane >> 4, lk = lg * 8;
  f32x4 acc1[2][4] = {}, acc2[2][4] = {};
  const int arow = rows[asr];
  for (int k0 = 0; k0 < D; k0 += 32) {
    {
      size_t ga = (size_t)arow * D + k0 + asc;
      *(f16x8*)&Ah[asr][asc]     = *(const f16x8*)(nhb + ga);
      *(f16x8*)&Ah[asr][asc + 8] = *(const f16x8*)(nhb + ga + 8);
      *(f16x8*)&Al[asr][asc]     = *(const f16x8*)(nlb + ga);
      *(f16x8*)&Al[asr][asc + 8] = *(const f16x8*)(nlb + ga + 8);
      size_t gb = (size_t)(col0 + bn2) * D + k0 + bkc;
      *(f16x8*)&B1h[bn2][bkc] = *(const f16x8*)(W1h + gb);
      *(f16x8*)&B1l[bn2][bkc] = *(const f16x8*)(W1l + gb);
      *(f16x8*)&B2h[bn2][bkc] = *(const f16x8*)(Wgh + gb);
      *(f16x8*)&B2l[bn2][bkc] = *(const f16x8*)(Wgl + gb);
    }
    __syncthreads();
    f16x8 a_h[2], a_l[2];
#pragma unroll
    for (int mt = 0; mt < 2; mt++) {
      a_h[mt] = *(const f16x8*)&Ah[w * 32 + mt * 16 + lm][lk];
      a_l[mt] = *(const f16x8*)&Al[w * 32 + mt * 16 + lm][lk];
    }
#pragma unroll
    for (int nt = 0; nt < 4; nt++) {
      f16x8 b_h = *(const f16x8*)&B1h[nt * 16 + lm][lk];
      f16x8 b_l = *(const f16x8*)&B1l[nt * 16 + lm][lk];
      f16x8 c_h = *(const f16x8*)&B2h[nt * 16 + lm][lk];
      f16x8 c_l = *(const f16x8*)&B2l[nt * 16 + lm][lk];
#pragma unroll
      for (int mt = 0; mt < 2; mt++) {
        f32x4 c1 = acc1[mt][nt];
        c1 = MFMA(a_h[mt], b_h, c1);
        c1 = MFMA(a_h[mt], b_l, c1);
        c1 = MFMA(a_l[mt], b_h, c1);
        acc1[mt][nt] = c1;
        f32x4 c2 = acc2[mt][nt];
        c2 = MFMA(a_h[mt], c_h, c2);
        c2 = MFMA(a_h[mt], c_l, c2);
        c2 = MFMA(a_l[mt], c_h, c2);
        acc2[mt][nt] = c2;
      }
    }
    __syncthreads();
  }
#pragma unroll
  for (int mt = 0; mt < 2; mt++)
#pragma unroll
    for (int nt = 0; nt < 4; nt++) {
      int col = col0 + nt * 16 + lm;
      float bb1 = b1f[e * FF + col], bb2 = bgf[e * FF + col];
#pragma unroll
      for (int r = 0; r < 4; r++) {
        int rit = w * 32 + mt * 16 + lg * 4 + r;
        if (rit < nv) {
          float z1 = acc1[mt][nt][r] + bb1;
          float zg = acc2[mt][nt][r] + bb2;
          float sl = z1 / (1.f + expf(-z1));
          float hv = sl * zg;
          f16 h16, l16; splitf(hv, h16, l16);
          hhb[(size_t)(base + rit) * FF + col] = h16;
          hlb[(size_t)(base + rit) * FF + col] = l16;
        }
      }
    }
}

// ---------------- MoE down-projection, 128x64 tiles, pre-split weights ----------------
// grid (MAXT, 4), 256 thr
__global__ __launch_bounds__(256) void k_ff2_mfma(
    const f16* __restrict__ hhb, const f16* __restrict__ hlb,
    const int* __restrict__ te, const int* __restrict__ tbase, const int* __restrict__ tnv,
    const f16* __restrict__ w2th, const f16* __restrict__ w2tl, const float* __restrict__ b2f,
    float* __restrict__ ybuf) {
  const int mt0 = blockIdx.x;
  const int e = te[mt0];
  if (e < 0) return;
  const int base = tbase[mt0], nv = tnv[mt0];
  const int col0 = blockIdx.y * 64;
  const f16* W2h = w2th + (size_t)e * FF * D;
  const f16* W2l = w2tl + (size_t)e * FF * D;
  __shared__ f16 Ah[128][44], Al[128][44], Bh[64][44], Bl[64][44];
  const int tid = threadIdx.x;
  const int asr = tid >> 1, asc = (tid & 1) * 16;
  const int bn2 = tid >> 2, bkc = (tid & 3) * 8;
  const int lane = tid & 63, w = tid >> 6;
  const int lm = lane & 15, lg = lane >> 4, lk = lg * 8;
  f32x4 acc[2][4] = {};
  for (int k0 = 0; k0 < FF; k0 += 32) {
    {
      size_t ga = (size_t)(base + asr) * FF + k0 + asc;
      *(f16x8*)&Ah[asr][asc]     = *(const f16x8*)(hhb + ga);
      *(f16x8*)&Ah[asr][asc + 8] = *(const f16x8*)(hhb + ga + 8);
      *(f16x8*)&Al[asr][asc]     = *(const f16x8*)(hlb + ga);
      *(f16x8*)&Al[asr][asc + 8] = *(const f16x8*)(hlb + ga + 8);
      size_t gb = (size_t)(col0 + bn2) * FF + k0 + bkc;
      *(f16x8*)&Bh[bn2][bkc] = *(const f16x8*)(W2h + gb);
      *(f16x8*)&Bl[bn2][bkc] = *(const f16x8*)(W2l + gb);
    }
    __syncthreads();
    f16x8 a_h[2], a_l[2];
#pragma unroll
    for (int mt = 0; mt < 2; mt++) {
      a_h[mt] = *(const f16x8*)&Ah[w * 32 + mt * 16 + lm][lk];
      a_l[mt] = *(const f16x8*)&Al[w * 32 + mt * 16 + lm][lk];
    }
#pragma unroll
    for (int nt = 0; nt < 4; nt++) {
      f16x8 b_h = *(const f16x8*)&Bh[nt * 16 + lm][lk];
      f16x8 b_l = *(const f16x8*)&Bl[nt * 16 + lm][lk];
#pragma unroll
      for (int mt = 0; mt < 2; mt++) {
        f32x4 c = acc[mt][nt];
        c = MFMA(a_h[mt], b_h, c);
        c = MFMA(a_h[mt], b_l, c);
        c = MFMA(a_l[mt], b_h, c);
        acc[mt][nt] = c;
      }
    }
    __syncthreads();
  }
#pragma unroll
  for (int mt = 0; mt < 2; mt++)
#pragma unroll
    for (int nt = 0; nt < 4; nt++) {
      int col = col0 + nt * 16 + lm;
      float bb = b2f[e * D + col];
#pragma unroll
      for (int r = 0; r < 4; r++) {
        int rit = w * 32 + mt * 16 + lg * 4 + r;
        if (rit < nv) ybuf[(size_t)(base + rit) * D + col] = acc[mt][nt][r] + bb;
      }
    }
}

// ---------------- wave-per-token: moe-sum + residual + LN2 + split ----------------
// grid 512, 256 thr
__global__ __launch_bounds__(256) void k_ln2(
    const float* __restrict__ ybuf, const int* __restrict__ tokpos,
    const float* __restrict__ norm, const float* __restrict__ s2, const float* __restrict__ b2,
    float* __restrict__ dst, f16* __restrict__ xh, f16* __restrict__ xl) {
  const int w = threadIdx.x >> 6, lane = threadIdx.x & 63;
  const int n = blockIdx.x * 4 + w;
  const int p0 = tokpos[n * 2 + 0], p1 = tokpos[n * 2 + 1];
  float val[4], s1v = 0.f, s2v = 0.f;
#pragma unroll
  for (int j = 0; j < 4; j++) {
    int d = lane + 64 * j;
    float v = ybuf[(size_t)p0 * D + d] + ybuf[(size_t)p1 * D + d] + norm[(size_t)n * D + d];
    val[j] = v; s1v += v; s2v += v * v;
  }
#pragma unroll
  for (int m = 1; m < 64; m <<= 1) {
    s1v += __shfl_xor(s1v, m);
    s2v += __shfl_xor(s2v, m);
  }
  float mean = s1v * (1.f / D);
  float var = s2v * (1.f / D) - mean * mean;
  float rstd = rsqrtf(var + EPS);
#pragma unroll
  for (int j = 0; j < 4; j++) {
    int d = lane + 64 * j;
    float ov = (val[j] - mean) * rstd * s2[d] + b2[d];
    dst[(size_t)n * D + d] = ov;
    f16 h16, l16; splitf(ov, h16, l16);
    xh[(size_t)n * D + d] = h16;
    xl[(size_t)n * D + d] = l16;
  }
}

extern "C" void kernel_launch(void* const* d_in, const int* in_sizes, int n_in,
                              void* d_out, int out_size, void* d_ws, size_t ws_size,
                              hipStream_t stream) {
  (void)in_sizes; (void)n_in; (void)out_size; (void)ws_size;
  const int*   tok = (const int*)d_in[0];
  const float* emb = (const float*)d_in[1];
  const float* Wq  = (const float*)d_in[2];
  const float* bq  = (const float*)d_in[3];
  const float* Wk  = (const float*)d_in[4];
  const float* bk  = (const float*)d_in[5];
  const float* Wv  = (const float*)d_in[6];
  const float* bv  = (const float*)d_in[7];
  const float* l1s = (const float*)d_in[8];
  const float* l1b = (const float*)d_in[9];
  const float* l2s = (const float*)d_in[10];
  const float* l2b = (const float*)d_in[11];
  const float* gW  = (const float*)d_in[12];
  const float* gb  = (const float*)d_in[13];
  const float* f1W = (const float*)d_in[14];
  const float* f1b = (const float*)d_in[15];
  const float* fgW = (const float*)d_in[16];
  const float* fgb = (const float*)d_in[17];
  const float* f2W = (const float*)d_in[18];
  const float* f2b = (const float*)d_in[19];
  float* out = (float*)d_out;

  char* p = (char*)d_ws;
  auto alloc = [&](size_t bytes) { char* r = p; p += (bytes + 255) & ~(size_t)255; return r; };
  // activations
  float* xb = (float*)alloc((size_t)NT * D * 4);
  f16* xh = (f16*)alloc((size_t)NT * D * 2);
  f16* xl = (f16*)alloc((size_t)NT * D * 2);
  f16* qhb = (f16*)alloc((size_t)NT * D * 2);
  f16* qlb = (f16*)alloc((size_t)NT * D * 2);
  f16* khb = (f16*)alloc((size_t)NT * D * 2);
  f16* klb = (f16*)alloc((size_t)NT * D * 2);
  f16* vhb = (f16*)alloc((size_t)NT * D * 2);
  f16* vlb = (f16*)alloc((size_t)NT * D * 2);
  float* ob = (float*)alloc((size_t)NT * D * 4);
  float* nb = (float*)alloc((size_t)NT * D * 4);
  f16* nhb = (f16*)alloc((size_t)NT * D * 2);
  f16* nlb = (f16*)alloc((size_t)NT * D * 2);
  f16* hhb = (f16*)alloc((size_t)PADROWS * FF * 2);
  f16* hlb = (f16*)alloc((size_t)PADROWS * FF * 2);
  float* yb = (float*)alloc((size_t)PADROWS * D * 4);
  int* eidx   = (int*)alloc((size_t)NT * 2 * 4);
  int* rlist  = (int*)alloc((size_t)PADROWS * 4);
  int* tokpos = (int*)alloc((size_t)NT * 2 * 4);
  int* te     = (int*)alloc(MAXT * 4);
  int* tbase  = (int*)alloc(MAXT * 4);
  int* tnv    = (int*)alloc(MAXT * 4);
  // pre-split/transposed weights
  size_t qkvsz = (size_t)LNUM * D * D;        // per hi/lo, elements
  size_t ffsz  = (size_t)LNUM * NE * D * FF;  // per hi/lo, elements
  f16* wqh = (f16*)alloc(qkvsz * 2); f16* wql = (f16*)alloc(qkvsz * 2);
  f16* wkh = (f16*)alloc(qkvsz * 2); f16* wkl = (f16*)alloc(qkvsz * 2);
  f16* wvh = (f16*)alloc(qkvsz * 2); f16* wvl = (f16*)alloc(qkvsz * 2);
  f16* w1th = (f16*)alloc(ffsz * 2); f16* w1tl = (f16*)alloc(ffsz * 2);
  f16* wgth = (f16*)alloc(ffsz * 2); f16* wgtl = (f16*)alloc(ffsz * 2);
  f16* w2th = (f16*)alloc(ffsz * 2); f16* w2tl = (f16*)alloc(ffsz * 2);

  // ---- weight prep (per launch; deterministic) ----
  k_wprep<<<dim3(D / 32, D / 32, LNUM), 256, 0, stream>>>(Wq, wqh, wql, D, D);
  k_wprep<<<dim3(D / 32, D / 32, LNUM), 256, 0, stream>>>(Wk, wkh, wkl, D, D);
  k_wprep<<<dim3(D / 32, D / 32, LNUM), 256, 0, stream>>>(Wv, wvh, wvl, D, D);
  k_wprep<<<dim3(FF / 32, D / 32, LNUM * NE), 256, 0, stream>>>(f1W, w1th, w1tl, D, FF);
  k_wprep<<<dim3(FF / 32, D / 32, LNUM * NE), 256, 0, stream>>>(fgW, wgth, wgtl, D, FF);
  k_wprep<<<dim3(D / 32, FF / 32, LNUM * NE), 256, 0, stream>>>(f2W, w2th, w2tl, FF, D);

  k_embed<<<NT, 256, 0, stream>>>(tok, emb, xb, xh, xl);

  for (int l = 0; l < LNUM; l++) {
    k_qkv_mfma<<<dim3(16, 4, 3), 256, 0, stream>>>(
        xh, xl,
        wqh + (size_t)l * D * D, wql + (size_t)l * D * D, bq + (size_t)l * D,
        wkh + (size_t)l * D * D, wkl + (size_t)l * D * D, bk + (size_t)l * D,
        wvh + (size_t)l * D * D, wvl + (size_t)l * D * D, bv + (size_t)l * D,
        qhb, qlb, khb, klb, vhb, vlb);
    k_attn_mfma<<<dim3(8, 32), 256, 0, stream>>>(qhb, qlb, khb, klb, vhb, vlb, ob);
    k_ln1gate<<<NT / 4, 256, 0, stream>>>(ob, xb, l1s + (size_t)l * D, l1b + (size_t)l * D,
                                          gW + (size_t)l * D * NE, gb + (size_t)l * NE,
                                          nb, nhb, nlb, eidx);
    k_route<<<1, 256, 0, stream>>>(eidx, rlist, tokpos, te, tbase, tnv);
    k_ff1_mfma<<<dim3(MAXT, 8), 256, 0, stream>>>(
        nhb, nlb, rlist, te, tbase, tnv,
        w1th + (size_t)l * NE * D * FF, w1tl + (size_t)l * NE * D * FF, f1b + (size_t)l * NE * FF,
        wgth + (size_t)l * NE * D * FF, wgtl + (size_t)l * NE * D * FF, fgb + (size_t)l * NE * FF,
        hhb, hlb);
    k_ff2_mfma<<<dim3(MAXT, 4), 256, 0, stream>>>(
        hhb, hlb, te, tbase, tnv,
        w2th + (size_t)l * NE * FF * D, w2tl + (size_t)l * NE * FF * D, f2b + (size_t)l * NE * D,
        yb);
    k_ln2<<<NT / 4, 256, 0, stream>>>(yb, tokpos, nb, l2s + (size_t)l * D, l2b + (size_t)l * D,
                                      (l == LNUM - 1) ? out : xb, xh, xl);
  }
}